// Round 3
// baseline (412.210 us; speedup 1.0000x reference)
//
#include <hip/hip_runtime.h>

// out[b,n] = sum_{c,hw} x[b,c,hw] * W_s[n,hw] * W_d[n,c] + W_b[n]
// B=512, C=384, N=512, HW=169 (13x13).
//
// R11: R10 post-mortem — partial-wave device atomics = 104 MB memory-side RMW
// traffic, atomic-throughput-bound. R9 post-mortem — cross-nb register state
// under 128-VGPR cap = scratch spill. Fix both by removing the combine from
// the hot kernel entirely:
//  - conv_part: waves tile n ONLY (each wave = all 96 c x 32 n, acc[6][2]).
//    Fold + 2 shfl_xor yields COMPLETE per-(b,c_blk,n) partials in-wave.
//    One barrier/block (post-staging). No atomics: plain stores to a 4 MB
//    part[c_blk][b][n] workspace slab.
//  - reduce_part: out = sum of 4 slabs + bias. 5 MB traffic, ~4 us.
//  - CT 96, Xs = 96*200*2 = 38.4 KB only -> 4 blocks/CU, launch_bounds(256,4).
//  - x read exactly once grid-wide (133 MB HBM floor); wsf/wdf/prep unchanged.
//  - Fallback chain: ws fits slab -> conv_part; ws fits wsf+wdf -> R8 kernel
//    (110 us proven); else LDS fallback.

#define B_   512
#define C_   384
#define N_   512
#define HW_  169
#define CT_F 96      // conv_part c-tile rows
#define CT   128     // R8 kernel / fallback c-tile rows
#define SXR  200     // Xs row stride in bf16 (16B-aligned rows, conflict-free b128)

#define WSF_ELEMS  ((size_t)32 * 6 * 64 * 8)       // 98,304 bf16
#define WDF_ELEMS  ((size_t)24 * 32 * 64 * 4)      // 196,608 f32
#define PART_ELEMS ((size_t)4 * B_ * N_)           // 1,048,576 f32 (4 MB)

typedef __bf16 bf16x8 __attribute__((ext_vector_type(8)));
typedef float f32x4  __attribute__((ext_vector_type(4)));
typedef float f32x4u __attribute__((ext_vector_type(4), aligned(4)));

__device__ __forceinline__ __bf16 f2bf(float f) {
  union { float f; unsigned u; } v; v.f = f;
  unsigned r = (v.u + 0x7FFFu + ((v.u >> 16) & 1u)) >> 16;   // RNE
  unsigned short s = (unsigned short)r;
  return __builtin_bit_cast(__bf16, s);
}

// hi16(a)|hi16(b)<<16 : two bf16 truncations in one v_perm
__device__ __forceinline__ unsigned pack_trunc(float a, float b) {
  return __builtin_amdgcn_perm(__builtin_bit_cast(unsigned, b),
                               __builtin_bit_cast(unsigned, a), 0x07060302u);
}

// ---------------- prep_aux: wsf (B-frag order) + wdf (C-layout order) ----------------
__global__ __launch_bounds__(256)
void prep_aux_kernel(const float* __restrict__ Ws,
                     const float* __restrict__ Wd,
                     __bf16* __restrict__ wsf,
                     float* __restrict__ wdf) {
  int t = blockIdx.x * 256 + threadIdx.x;      // 61440 total, exact
  if (t < 12288) {
    // wsf: t = (nm*6 + kb)*64 + lane ; lane(q=l>>4,m=l&15) holds Ws[nm*16+m][kb*32+q*8+j]
    int lane = t & 63;
    int fr   = t >> 6;
    int kb   = fr % 6;
    int nm   = fr / 6;
    int n    = nm * 16 + (lane & 15);
    int k0   = kb * 32 + (lane >> 4) * 8;
    const float* src = Ws + (size_t)n * HW_;
    bf16x8 v;
    #pragma unroll
    for (int j = 0; j < 8; ++j) {
      int k = k0 + j;
      float f = (k < HW_) ? src[k] : 0.f;
      v[j] = f2bf(f);
    }
    *(bf16x8*)(wsf + (size_t)t * 8) = v;
  } else {
    // wdf: t2 = (cm*32 + nm)*64 + lane; elem i = Wd[nm*16+(l&15)][cm*16+(l>>4)*4+i]
    int t2 = t - 12288;
    int lane = t2 & 63;
    int fr   = t2 >> 6;
    int nm   = fr & 31;
    int cm   = fr >> 5;
    int n    = nm * 16 + (lane & 15);
    int c0   = cm * 16 + (lane >> 4) * 4;
    f32x4 w = *(const f32x4u*)(Wd + (size_t)n * C_ + c0);
    *(f32x4*)(wdf + (size_t)t2 * 4) = w;
  }
}

// ---------------- R11 main kernel: per-(b,c_blk) complete partials, no atomics ----------------
__global__ __launch_bounds__(256, 4)
void conv_part(const float* __restrict__ x,
               const __bf16* __restrict__ wsf,
               const float* __restrict__ wdf,
               float* __restrict__ part) {
  __shared__ __align__(16) __bf16 Xs[CT_F * SXR];   // 38,400 B; the ONLY LDS

  const int tid  = threadIdx.x;
  // XCD swizzle: the 4 c_blks of one b land on the same id%8 slot.
  const int id    = blockIdx.x;     // 0..2047
  const int slot  = id & 7;
  const int t8    = id >> 3;        // 0..255
  const int c_blk = t8 & 3;
  const int b     = (t8 >> 2) * 8 + slot;

  const int lane  = tid & 63;
  const int wv    = tid >> 6;          // 4 waves, each owns ALL c x 32 n
  const int lrow  = lane & 15;
  const int lquad = lane >> 4;

  // ---- stage X tile: 96 rows x 169 cols fp32 -> bf16 (cols padded to 192) ----
  const float* src = x + ((size_t)b * C_ + (size_t)c_blk * CT_F) * HW_;
  // 96 rows x 48 chunks(4 cols) = 4608 items = 18/thread exact
  #pragma unroll 6
  for (int p = 0; p < 18; ++p) {
    int i   = p * 256 + tid;
    int row = i / 48;
    int ch  = i - row * 48;
    const float* bp = src + row * HW_ + ch * 4;
    float v0 = 0.f, v1 = 0.f, v2 = 0.f, v3 = 0.f;
    if (ch < 42) {                      // cols ch*4..+3 <= 167
      f32x4u t = *(const f32x4u*)bp;
      v0 = t[0]; v1 = t[1]; v2 = t[2]; v3 = t[3];
    } else if (ch == 42) {              // only col 168 valid
      v0 = bp[0];
    }                                    // ch 43..47: zero pad to col 191
    unsigned d0 = pack_trunc(v0, v1);
    unsigned d1 = pack_trunc(v2, v3);
    uint2 d; d.x = d0; d.y = d1;
    *(uint2*)&Xs[row * SXR + ch * 4] = d;
  }
  __syncthreads();   // the ONLY barrier in this kernel

  float* pb = part + ((size_t)c_blk * B_ + b) * N_;

  // ---- 4 n-tiles; wave wv owns nm = nb*8 + wv*2 + {0,1} (32 n per nb) ----
  #pragma unroll 1
  for (int nb = 0; nb < 4; ++nb) {
    const int nm0 = nb * 8 + wv * 2;          // global 16-n fragment row (0..31)
    const __bf16* bbase = wsf + ((size_t)nm0 * 6) * 512 + (size_t)lane * 8;

    const f32x4 zero = {0.f, 0.f, 0.f, 0.f};
    f32x4 acc[6][2];
    #pragma unroll
    for (int mi = 0; mi < 6; ++mi)
      #pragma unroll
      for (int ni = 0; ni < 2; ++ni)
        acc[mi][ni] = zero;

    #pragma unroll
    for (int kb = 0; kb < 6; ++kb) {
      bf16x8 afr[6], bfr[2];
      #pragma unroll
      for (int mi = 0; mi < 6; ++mi)
        afr[mi] = *(const bf16x8*)&Xs[(mi * 16 + lrow) * SXR + kb * 32 + lquad * 8];
      #pragma unroll
      for (int ni = 0; ni < 2; ++ni)
        bfr[ni] = *(const bf16x8*)(bbase + ((size_t)ni * 6 + kb) * 512);
      #pragma unroll
      for (int mi = 0; mi < 6; ++mi)
        #pragma unroll
        for (int ni = 0; ni < 2; ++ni)
          acc[mi][ni] = __builtin_amdgcn_mfma_f32_16x16x32_bf16(
              afr[mi], bfr[ni], acc[mi][ni], 0, 0, 0);
    }

    // fold acc * W_d (wdf C-layout, R7-proven) over ALL 6 mi, then quad-combine:
    // lanes {m,m+16,m+32,m+48} hold disjoint c-quarters of the same n.
    #pragma unroll
    for (int ni = 0; ni < 2; ++ni) {
      float t = 0.f;
      #pragma unroll
      for (int mi = 0; mi < 6; ++mi) {
        const f32x4 w = *(const f32x4*)(wdf +
            (((size_t)(c_blk * 6 + mi) * 32 + (nm0 + ni)) * 256 + (size_t)lane * 4));
        t += acc[mi][ni][0] * w[0] + acc[mi][ni][1] * w[1]
           + acc[mi][ni][2] * w[2] + acc[mi][ni][3] * w[3];
      }
      t += __shfl_xor(t, 16, 64);
      t += __shfl_xor(t, 32, 64);
      if (lane < 16)
        pb[(nm0 + ni) * 16 + lrow] = t;      // plain store, no atomic
    }
  }
}

// ---------------- reducer: out = sum_cb part[cb] + bias ----------------
__global__ __launch_bounds__(256)
void reduce_part(const float* __restrict__ part,
                 const float* __restrict__ Wb,
                 float* __restrict__ out) {
  const size_t S = (size_t)B_ * N_;
  int idx = (blockIdx.x * 256 + threadIdx.x) * 4;   // 256 blocks -> covers 262144
  f32x4 a0 = *(const f32x4u*)(part + idx);
  f32x4 a1 = *(const f32x4u*)(part + S + idx);
  f32x4 a2 = *(const f32x4u*)(part + 2 * S + idx);
  f32x4 a3 = *(const f32x4u*)(part + 3 * S + idx);
  f32x4 wb = *(const f32x4u*)(Wb + (idx & (N_ - 1)));
  f32x4 r;
  #pragma unroll
  for (int i = 0; i < 4; ++i)
    r[i] = a0[i] + a1[i] + a2[i] + a3[i] + wb[i];
  *(f32x4*)(out + idx) = r;
}

// ---------------- R8 main kernel (ws fits wsf+wdf only; 110 us proven) ----------------
__global__ __launch_bounds__(256, 3)
void conv_fused_v8(const float* __restrict__ x,
                   const __bf16* __restrict__ wsf,
                   const float* __restrict__ wdf,
                   const float* __restrict__ Wb,
                   float* __restrict__ out) {
  __shared__ __align__(16) __bf16 Xs[CT * SXR];   // 51.2 KB
  __shared__ float red[4][64];                     // 1 KB

  const int tid  = threadIdx.x;
  const int id    = blockIdx.x;     // 0..1535
  const int slot  = id & 7;
  const int t8    = id >> 3;        // 0..191
  const int c_blk = t8 % 3;
  const int b     = (t8 / 3) * 8 + slot;

  const int lane  = tid & 63;
  const int wv    = tid >> 6;          // 4 waves: 2x2 (c,n) 64x64 quadrants
  const int cq    = (wv >> 1) * 64;
  const int nq    = (wv & 1) * 64;
  const int lrow  = lane & 15;
  const int lquad = lane >> 4;

  const float* src = x + ((size_t)b * C_ + (size_t)c_blk * CT) * HW_;
  #pragma unroll 4
  for (int p = 0; p < 24; ++p) {
    int i   = p * 256 + tid;
    int row = i / 48;
    int ch  = i - row * 48;
    const float* bp = src + row * HW_ + ch * 4;
    float v0 = 0.f, v1 = 0.f, v2 = 0.f, v3 = 0.f;
    if (ch < 42) {
      f32x4u t = *(const f32x4u*)bp;
      v0 = t[0]; v1 = t[1]; v2 = t[2]; v3 = t[3];
    } else if (ch == 42) {
      v0 = bp[0];
    }
    unsigned d0 = pack_trunc(v0, v1);
    unsigned d1 = pack_trunc(v2, v3);
    uint2 d; d.x = d0; d.y = d1;
    *(uint2*)&Xs[row * SXR + ch * 4] = d;
  }
  __syncthreads();

  const int cm0 = c_blk * 8 + (cq >> 4);

  #pragma unroll 1
  for (int nb = 0; nb < 4; ++nb) {
    const int nm0 = nb * 8 + (nq >> 4);
    const __bf16* bbase = wsf + ((size_t)nm0 * 6) * 512 + (size_t)lane * 8;

    const f32x4 zero = {0.f, 0.f, 0.f, 0.f};
    f32x4 acc[4][4];
    #pragma unroll
    for (int mi = 0; mi < 4; ++mi)
      #pragma unroll
      for (int ni = 0; ni < 4; ++ni)
        acc[mi][ni] = zero;

    #pragma unroll
    for (int kb = 0; kb < 6; ++kb) {
      bf16x8 afr[4], bfr[4];
      #pragma unroll
      for (int mi = 0; mi < 4; ++mi)
        afr[mi] = *(const bf16x8*)&Xs[(cq + mi * 16 + lrow) * SXR + kb * 32 + lquad * 8];
      #pragma unroll
      for (int ni = 0; ni < 4; ++ni)
        bfr[ni] = *(const bf16x8*)(bbase + ((size_t)ni * 6 + kb) * 512);
      #pragma unroll
      for (int mi = 0; mi < 4; ++mi)
        #pragma unroll
        for (int ni = 0; ni < 4; ++ni)
          acc[mi][ni] = __builtin_amdgcn_mfma_f32_16x16x32_bf16(
              afr[mi], bfr[ni], acc[mi][ni], 0, 0, 0);
    }

    float s[4] = {0.f, 0.f, 0.f, 0.f};
    #pragma unroll
    for (int ni = 0; ni < 4; ++ni) {
      #pragma unroll
      for (int mi = 0; mi < 4; ++mi) {
        const f32x4 w = *(const f32x4*)(wdf +
            (((size_t)(cm0 + mi) * 32 + (nm0 + ni)) * 64 + lane) * 4);
        s[ni] += acc[mi][ni][0] * w[0] + acc[mi][ni][1] * w[1]
               + acc[mi][ni][2] * w[2] + acc[mi][ni][3] * w[3];
      }
    }

    #pragma unroll
    for (int ni = 0; ni < 4; ++ni) {
      s[ni] += __shfl_xor(s[ni], 16, 64);
      s[ni] += __shfl_xor(s[ni], 32, 64);
    }
    if (lane < 16) {
      #pragma unroll
      for (int ni = 0; ni < 4; ++ni)
        red[wv][ni * 16 + lrow] = s[ni];
    }
    __syncthreads();

    if (tid < 128) {
      const int half = tid >> 6;
      const int idx  = tid & 63;
      const int n    = nb * 128 + tid;
      float v = red[half][idx] + red[half + 2][idx];
      if (c_blk == 0) v += Wb[n];
      atomicAdd(&out[(size_t)b * N_ + n], v);
    }
    __syncthreads();
  }
}

// ---------------- fallback main kernel (no workspace needed) ----------------

#define LDSS 104
#define KCH  96
#define NT   128

__global__ __launch_bounds__(256)
void conv_main_fallback(const float* __restrict__ x,
                        const float* __restrict__ Ws_g,
                        const float* __restrict__ Wd,
                        const float* __restrict__ Wb,
                        float* __restrict__ out) {
  __shared__ __align__(16) __bf16 Xs[CT][LDSS];
  __shared__ __align__(16) __bf16 Ws[NT][LDSS];

  const int tid   = threadIdx.x;
  const int n_blk = blockIdx.x;
  const int c_blk = blockIdx.y;
  const int b     = blockIdx.z;
  const int c0 = c_blk * CT;
  const int n0 = n_blk * NT;
  const int lane  = tid & 63;
  const int wv    = tid >> 6;
  const int cq    = (wv >> 1) * 64;
  const int nq    = (wv & 1) * 64;
  const int lrow  = lane & 15;
  const int lquad = lane >> 4;

  const f32x4 zero = {0.f, 0.f, 0.f, 0.f};
  f32x4 acc[4][4];
  #pragma unroll
  for (int mi = 0; mi < 4; ++mi)
    #pragma unroll
    for (int ni = 0; ni < 4; ++ni)
      acc[mi][ni] = zero;

  const float* xb  = x    + (size_t)b  * (C_ * HW_) + (size_t)c0 * HW_;
  const float* wsb = Ws_g + (size_t)n0 * HW_;

  for (int ch = 0; ch < 2; ++ch) {
    const int k0 = ch * KCH;
    __syncthreads();
    for (int e = tid; e < CT * KCH; e += 256) {
      int r   = e / KCH;
      int col = e - r * KCH;
      int k   = k0 + col;
      float vx = 0.f, vw = 0.f;
      if (k < HW_) {
        vx = xb [r * HW_ + k];
        vw = wsb[r * HW_ + k];
      }
      Xs[r][col] = f2bf(vx);
      Ws[r][col] = f2bf(vw);
    }
    __syncthreads();

    #pragma unroll
    for (int ks = 0; ks < 3; ++ks) {
      const int kc = ks * 32 + lquad * 8;
      bf16x8 afr[4], bfr[4];
      #pragma unroll
      for (int mi = 0; mi < 4; ++mi)
        afr[mi] = *(const bf16x8*)&Xs[cq + mi * 16 + lrow][kc];
      #pragma unroll
      for (int ni = 0; ni < 4; ++ni)
        bfr[ni] = *(const bf16x8*)&Ws[nq + ni * 16 + lrow][kc];
      #pragma unroll
      for (int mi = 0; mi < 4; ++mi)
        #pragma unroll
        for (int ni = 0; ni < 4; ++ni)
          acc[mi][ni] = __builtin_amdgcn_mfma_f32_16x16x32_bf16(
              afr[mi], bfr[ni], acc[mi][ni], 0, 0, 0);
    }
  }

  #pragma unroll
  for (int ni = 0; ni < 4; ++ni) {
    const int n = n0 + nq + ni * 16 + lrow;
    float sv = 0.f;
    #pragma unroll
    for (int mi = 0; mi < 4; ++mi) {
      const int cbase = c0 + cq + mi * 16 + lquad * 4;
      #pragma unroll
      for (int i = 0; i < 4; ++i)
        sv += acc[mi][ni][i] * Wd[(size_t)n * C_ + (cbase + i)];
    }
    sv += __shfl_xor(sv, 16, 64);
    sv += __shfl_xor(sv, 32, 64);
    if (lane < 16) {
      if (c_blk == 0 && cq == 0) sv += Wb[n];
      atomicAdd(&out[(size_t)b * N_ + n], sv);
    }
  }
}

extern "C" void kernel_launch(void* const* d_in, const int* in_sizes, int n_in,
                              void* d_out, int out_size, void* d_ws, size_t ws_size,
                              hipStream_t stream) {
  const float* x   = (const float*)d_in[0];   // [512,384,13,13]
  const float* Wsp = (const float*)d_in[1];   // [512,13,13]
  const float* Wd  = (const float*)d_in[2];   // [512,384]
  const float* Wb  = (const float*)d_in[3];   // [1,512]
  float* out = (float*)d_out;                 // [512,512] fp32

  const size_t need_basic = WSF_ELEMS * sizeof(__bf16) + WDF_ELEMS * sizeof(float);
  const size_t need_full  = need_basic + PART_ELEMS * sizeof(float);

  if (ws_size >= need_full) {
    __bf16* wsf  = (__bf16*)d_ws;
    float*  wdf  = (float*)(wsf + WSF_ELEMS);
    float*  partb = wdf + WDF_ELEMS;

    prep_aux_kernel<<<240, 256, 0, stream>>>(Wsp, Wd, wsf, wdf);
    conv_part<<<2048, 256, 0, stream>>>(x, wsf, wdf, partb);
    reduce_part<<<256, 256, 0, stream>>>(partb, Wb, out);
  } else if (ws_size >= need_basic) {
    __bf16* wsf = (__bf16*)d_ws;
    float*  wdf = (float*)(wsf + WSF_ELEMS);

    hipMemsetAsync(d_out, 0, (size_t)out_size * sizeof(float), stream);
    prep_aux_kernel<<<240, 256, 0, stream>>>(Wsp, Wd, wsf, wdf);
    conv_fused_v8<<<1536, 256, 0, stream>>>(x, wsf, wdf, Wb, out);
  } else {
    hipMemsetAsync(d_out, 0, (size_t)out_size * sizeof(float), stream);
    dim3 grid(N_ / NT, C_ / CT, B_);
    conv_main_fallback<<<grid, 256, 0, stream>>>(x, Wsp, Wd, Wb, out);
  }
}

// Round 4
// 346.613 us; speedup vs baseline: 1.1893x; 1.1893x over previous
//
#include <hip/hip_runtime.h>

// out[b,n] = sum_{c,hw} x[b,c,hw] * W_s[n,hw] * W_d[n,c] + W_b[n]
// B=512, C=384, N=512, HW=169 (13x13).
//
// R12: single-variable fix of R11. Post-mortem chain:
//   R8  (launch_bounds(256,3)): VGPR=72, no spill, 110 us.
//   R9/R10/R11 (launch_bounds(256,4)): VGPR=64 (the 8-waves/SIMD cap!) ->
//   massive scratch spill (R11: FETCH 597 MB vs 133 MB input, WRITE 262 MB
//   vs 4 MB of real stores). hipcc maps ",4" to a 64-VGPR budget, not 128.
// Fix: conv_part keeps the R11 structure (complete in-wave partials, no
// atomics, 1 barrier/block, 4 MB part slab + tiny reducer) but drops the
// min-occupancy arg: __launch_bounds__(256) only. Natural ~90-110 VGPR
// <= 128 -> HW gives 4 waves/SIMD; LDS 38.4 KB -> 4 blocks/CU.
// Verification signal: VGPR_Count must NOT be 64; WRITE_SIZE ~4 MB.

#define B_   512
#define C_   384
#define N_   512
#define HW_  169
#define CT_F 96      // conv_part c-tile rows
#define CT   128     // R8 kernel / fallback c-tile rows
#define SXR  200     // Xs row stride in bf16 (16B-aligned rows)

#define WSF_ELEMS  ((size_t)32 * 6 * 64 * 8)       // 98,304 bf16
#define WDF_ELEMS  ((size_t)24 * 32 * 64 * 4)      // 196,608 f32
#define PART_ELEMS ((size_t)4 * B_ * N_)           // 1,048,576 f32 (4 MB)

typedef __bf16 bf16x8 __attribute__((ext_vector_type(8)));
typedef float f32x4  __attribute__((ext_vector_type(4)));
typedef float f32x4u __attribute__((ext_vector_type(4), aligned(4)));

__device__ __forceinline__ __bf16 f2bf(float f) {
  union { float f; unsigned u; } v; v.f = f;
  unsigned r = (v.u + 0x7FFFu + ((v.u >> 16) & 1u)) >> 16;   // RNE
  unsigned short s = (unsigned short)r;
  return __builtin_bit_cast(__bf16, s);
}

// hi16(a)|hi16(b)<<16 : two bf16 truncations in one v_perm
__device__ __forceinline__ unsigned pack_trunc(float a, float b) {
  return __builtin_amdgcn_perm(__builtin_bit_cast(unsigned, b),
                               __builtin_bit_cast(unsigned, a), 0x07060302u);
}

// ---------------- prep_aux: wsf (B-frag order) + wdf (C-layout order) ----------------
__global__ __launch_bounds__(256)
void prep_aux_kernel(const float* __restrict__ Ws,
                     const float* __restrict__ Wd,
                     __bf16* __restrict__ wsf,
                     float* __restrict__ wdf) {
  int t = blockIdx.x * 256 + threadIdx.x;      // 61440 total, exact
  if (t < 12288) {
    // wsf: t = (nm*6 + kb)*64 + lane ; lane(q=l>>4,m=l&15) holds Ws[nm*16+m][kb*32+q*8+j]
    int lane = t & 63;
    int fr   = t >> 6;
    int kb   = fr % 6;
    int nm   = fr / 6;
    int n    = nm * 16 + (lane & 15);
    int k0   = kb * 32 + (lane >> 4) * 8;
    const float* src = Ws + (size_t)n * HW_;
    bf16x8 v;
    #pragma unroll
    for (int j = 0; j < 8; ++j) {
      int k = k0 + j;
      float f = (k < HW_) ? src[k] : 0.f;
      v[j] = f2bf(f);
    }
    *(bf16x8*)(wsf + (size_t)t * 8) = v;
  } else {
    // wdf: t2 = (cm*32 + nm)*64 + lane; elem i = Wd[nm*16+(l&15)][cm*16+(l>>4)*4+i]
    int t2 = t - 12288;
    int lane = t2 & 63;
    int fr   = t2 >> 6;
    int nm   = fr & 31;
    int cm   = fr >> 5;
    int n    = nm * 16 + (lane & 15);
    int c0   = cm * 16 + (lane >> 4) * 4;
    f32x4 w = *(const f32x4u*)(Wd + (size_t)n * C_ + c0);
    *(f32x4*)(wdf + (size_t)t2 * 4) = w;
  }
}

// ---------------- R12 main kernel: per-(b,c_blk) complete partials, no atomics ----------------
__global__ __launch_bounds__(256)          // NO min-occupancy arg: avoid the 64-VGPR cap
void conv_part(const float* __restrict__ x,
               const __bf16* __restrict__ wsf,
               const float* __restrict__ wdf,
               float* __restrict__ part) {
  __shared__ __align__(16) __bf16 Xs[CT_F * SXR];   // 38,400 B; the ONLY LDS

  const int tid  = threadIdx.x;
  // XCD swizzle: the 4 c_blks of one b land on the same id%8 slot.
  const int id    = blockIdx.x;     // 0..2047
  const int slot  = id & 7;
  const int t8    = id >> 3;        // 0..255
  const int c_blk = t8 & 3;
  const int b     = (t8 >> 2) * 8 + slot;

  const int lane  = tid & 63;
  const int wv    = tid >> 6;          // 4 waves, each owns ALL c x 32 n
  const int lrow  = lane & 15;
  const int lquad = lane >> 4;

  // ---- stage X tile: 96 rows x 169 cols fp32 -> bf16 (cols padded to 192) ----
  const float* src = x + ((size_t)b * C_ + (size_t)c_blk * CT_F) * HW_;
  // 96 rows x 48 chunks(4 cols) = 4608 items = 18/thread exact
  #pragma unroll 6
  for (int p = 0; p < 18; ++p) {
    int i   = p * 256 + tid;
    int row = i / 48;
    int ch  = i - row * 48;
    const float* bp = src + row * HW_ + ch * 4;
    float v0 = 0.f, v1 = 0.f, v2 = 0.f, v3 = 0.f;
    if (ch < 42) {                      // cols ch*4..+3 <= 167
      f32x4u t = *(const f32x4u*)bp;
      v0 = t[0]; v1 = t[1]; v2 = t[2]; v3 = t[3];
    } else if (ch == 42) {              // only col 168 valid
      v0 = bp[0];
    }                                    // ch 43..47: zero pad to col 191
    unsigned d0 = pack_trunc(v0, v1);
    unsigned d1 = pack_trunc(v2, v3);
    uint2 d; d.x = d0; d.y = d1;
    *(uint2*)&Xs[row * SXR + ch * 4] = d;
  }
  __syncthreads();   // the ONLY barrier in this kernel

  float* pb = part + ((size_t)c_blk * B_ + b) * N_;

  // ---- 4 n-tiles; wave wv owns nm = nb*8 + wv*2 + {0,1} (32 n per nb) ----
  #pragma unroll 1
  for (int nb = 0; nb < 4; ++nb) {
    const int nm0 = nb * 8 + wv * 2;          // global 16-n fragment row (0..31)
    const __bf16* bbase = wsf + ((size_t)nm0 * 6) * 512 + (size_t)lane * 8;

    const f32x4 zero = {0.f, 0.f, 0.f, 0.f};
    f32x4 acc[6][2];
    #pragma unroll
    for (int mi = 0; mi < 6; ++mi)
      #pragma unroll
      for (int ni = 0; ni < 2; ++ni)
        acc[mi][ni] = zero;

    #pragma unroll
    for (int kb = 0; kb < 6; ++kb) {
      bf16x8 afr[6], bfr[2];
      #pragma unroll
      for (int mi = 0; mi < 6; ++mi)
        afr[mi] = *(const bf16x8*)&Xs[(mi * 16 + lrow) * SXR + kb * 32 + lquad * 8];
      #pragma unroll
      for (int ni = 0; ni < 2; ++ni)
        bfr[ni] = *(const bf16x8*)(bbase + ((size_t)ni * 6 + kb) * 512);
      #pragma unroll
      for (int mi = 0; mi < 6; ++mi)
        #pragma unroll
        for (int ni = 0; ni < 2; ++ni)
          acc[mi][ni] = __builtin_amdgcn_mfma_f32_16x16x32_bf16(
              afr[mi], bfr[ni], acc[mi][ni], 0, 0, 0);
    }

    // fold acc * W_d (wdf C-layout, R7-proven) over ALL 6 mi, then quad-combine:
    // lanes {m,m+16,m+32,m+48} hold disjoint c-quarters of the same n.
    #pragma unroll
    for (int ni = 0; ni < 2; ++ni) {
      float t = 0.f;
      #pragma unroll
      for (int mi = 0; mi < 6; ++mi) {
        const f32x4 w = *(const f32x4*)(wdf +
            (((size_t)(c_blk * 6 + mi) * 32 + (nm0 + ni)) * 256 + (size_t)lane * 4));
        t += acc[mi][ni][0] * w[0] + acc[mi][ni][1] * w[1]
           + acc[mi][ni][2] * w[2] + acc[mi][ni][3] * w[3];
      }
      t += __shfl_xor(t, 16, 64);
      t += __shfl_xor(t, 32, 64);
      if (lane < 16)
        pb[(nm0 + ni) * 16 + lrow] = t;      // plain store, no atomic
    }
  }
}

// ---------------- reducer: out = sum_cb part[cb] + bias ----------------
__global__ __launch_bounds__(256)
void reduce_part(const float* __restrict__ part,
                 const float* __restrict__ Wb,
                 float* __restrict__ out) {
  const size_t S = (size_t)B_ * N_;
  int idx = (blockIdx.x * 256 + threadIdx.x) * 4;   // 256 blocks -> covers 262144
  f32x4 a0 = *(const f32x4u*)(part + idx);
  f32x4 a1 = *(const f32x4u*)(part + S + idx);
  f32x4 a2 = *(const f32x4u*)(part + 2 * S + idx);
  f32x4 a3 = *(const f32x4u*)(part + 3 * S + idx);
  f32x4 wb = *(const f32x4u*)(Wb + (idx & (N_ - 1)));
  f32x4 r;
  #pragma unroll
  for (int i = 0; i < 4; ++i)
    r[i] = a0[i] + a1[i] + a2[i] + a3[i] + wb[i];
  *(f32x4*)(out + idx) = r;
}

// ---------------- R8 main kernel (ws fits wsf+wdf only; 110 us proven) ----------------
__global__ __launch_bounds__(256, 3)
void conv_fused_v8(const float* __restrict__ x,
                   const __bf16* __restrict__ wsf,
                   const float* __restrict__ wdf,
                   const float* __restrict__ Wb,
                   float* __restrict__ out) {
  __shared__ __align__(16) __bf16 Xs[CT * SXR];   // 51.2 KB
  __shared__ float red[4][64];                     // 1 KB

  const int tid  = threadIdx.x;
  const int id    = blockIdx.x;     // 0..1535
  const int slot  = id & 7;
  const int t8    = id >> 3;        // 0..191
  const int c_blk = t8 % 3;
  const int b     = (t8 / 3) * 8 + slot;

  const int lane  = tid & 63;
  const int wv    = tid >> 6;          // 4 waves: 2x2 (c,n) 64x64 quadrants
  const int cq    = (wv >> 1) * 64;
  const int nq    = (wv & 1) * 64;
  const int lrow  = lane & 15;
  const int lquad = lane >> 4;

  const float* src = x + ((size_t)b * C_ + (size_t)c_blk * CT) * HW_;
  #pragma unroll 4
  for (int p = 0; p < 24; ++p) {
    int i   = p * 256 + tid;
    int row = i / 48;
    int ch  = i - row * 48;
    const float* bp = src + row * HW_ + ch * 4;
    float v0 = 0.f, v1 = 0.f, v2 = 0.f, v3 = 0.f;
    if (ch < 42) {
      f32x4u t = *(const f32x4u*)bp;
      v0 = t[0]; v1 = t[1]; v2 = t[2]; v3 = t[3];
    } else if (ch == 42) {
      v0 = bp[0];
    }
    unsigned d0 = pack_trunc(v0, v1);
    unsigned d1 = pack_trunc(v2, v3);
    uint2 d; d.x = d0; d.y = d1;
    *(uint2*)&Xs[row * SXR + ch * 4] = d;
  }
  __syncthreads();

  const int cm0 = c_blk * 8 + (cq >> 4);

  #pragma unroll 1
  for (int nb = 0; nb < 4; ++nb) {
    const int nm0 = nb * 8 + (nq >> 4);
    const __bf16* bbase = wsf + ((size_t)nm0 * 6) * 512 + (size_t)lane * 8;

    const f32x4 zero = {0.f, 0.f, 0.f, 0.f};
    f32x4 acc[4][4];
    #pragma unroll
    for (int mi = 0; mi < 4; ++mi)
      #pragma unroll
      for (int ni = 0; ni < 4; ++ni)
        acc[mi][ni] = zero;

    #pragma unroll
    for (int kb = 0; kb < 6; ++kb) {
      bf16x8 afr[4], bfr[4];
      #pragma unroll
      for (int mi = 0; mi < 4; ++mi)
        afr[mi] = *(const bf16x8*)&Xs[(cq + mi * 16 + lrow) * SXR + kb * 32 + lquad * 8];
      #pragma unroll
      for (int ni = 0; ni < 4; ++ni)
        bfr[ni] = *(const bf16x8*)(bbase + ((size_t)ni * 6 + kb) * 512);
      #pragma unroll
      for (int mi = 0; mi < 4; ++mi)
        #pragma unroll
        for (int ni = 0; ni < 4; ++ni)
          acc[mi][ni] = __builtin_amdgcn_mfma_f32_16x16x32_bf16(
              afr[mi], bfr[ni], acc[mi][ni], 0, 0, 0);
    }

    float s[4] = {0.f, 0.f, 0.f, 0.f};
    #pragma unroll
    for (int ni = 0; ni < 4; ++ni) {
      #pragma unroll
      for (int mi = 0; mi < 4; ++mi) {
        const f32x4 w = *(const f32x4*)(wdf +
            (((size_t)(cm0 + mi) * 32 + (nm0 + ni)) * 64 + lane) * 4);
        s[ni] += acc[mi][ni][0] * w[0] + acc[mi][ni][1] * w[1]
               + acc[mi][ni][2] * w[2] + acc[mi][ni][3] * w[3];
      }
    }

    #pragma unroll
    for (int ni = 0; ni < 4; ++ni) {
      s[ni] += __shfl_xor(s[ni], 16, 64);
      s[ni] += __shfl_xor(s[ni], 32, 64);
    }
    if (lane < 16) {
      #pragma unroll
      for (int ni = 0; ni < 4; ++ni)
        red[wv][ni * 16 + lrow] = s[ni];
    }
    __syncthreads();

    if (tid < 128) {
      const int half = tid >> 6;
      const int idx  = tid & 63;
      const int n    = nb * 128 + tid;
      float v = red[half][idx] + red[half + 2][idx];
      if (c_blk == 0) v += Wb[n];
      atomicAdd(&out[(size_t)b * N_ + n], v);
    }
    __syncthreads();
  }
}

// ---------------- fallback main kernel (no workspace needed) ----------------

#define LDSS 104
#define KCH  96
#define NT   128

__global__ __launch_bounds__(256)
void conv_main_fallback(const float* __restrict__ x,
                        const float* __restrict__ Ws_g,
                        const float* __restrict__ Wd,
                        const float* __restrict__ Wb,
                        float* __restrict__ out) {
  __shared__ __align__(16) __bf16 Xs[CT][LDSS];
  __shared__ __align__(16) __bf16 Ws[NT][LDSS];

  const int tid   = threadIdx.x;
  const int n_blk = blockIdx.x;
  const int c_blk = blockIdx.y;
  const int b     = blockIdx.z;
  const int c0 = c_blk * CT;
  const int n0 = n_blk * NT;
  const int lane  = tid & 63;
  const int wv    = tid >> 6;
  const int cq    = (wv >> 1) * 64;
  const int nq    = (wv & 1) * 64;
  const int lrow  = lane & 15;
  const int lquad = lane >> 4;

  const f32x4 zero = {0.f, 0.f, 0.f, 0.f};
  f32x4 acc[4][4];
  #pragma unroll
  for (int mi = 0; mi < 4; ++mi)
    #pragma unroll
    for (int ni = 0; ni < 4; ++ni)
      acc[mi][ni] = zero;

  const float* xb  = x    + (size_t)b  * (C_ * HW_) + (size_t)c0 * HW_;
  const float* wsb = Ws_g + (size_t)n0 * HW_;

  for (int ch = 0; ch < 2; ++ch) {
    const int k0 = ch * KCH;
    __syncthreads();
    for (int e = tid; e < CT * KCH; e += 256) {
      int r   = e / KCH;
      int col = e - r * KCH;
      int k   = k0 + col;
      float vx = 0.f, vw = 0.f;
      if (k < HW_) {
        vx = xb [r * HW_ + k];
        vw = wsb[r * HW_ + k];
      }
      Xs[r][col] = f2bf(vx);
      Ws[r][col] = f2bf(vw);
    }
    __syncthreads();

    #pragma unroll
    for (int ks = 0; ks < 3; ++ks) {
      const int kc = ks * 32 + lquad * 8;
      bf16x8 afr[4], bfr[4];
      #pragma unroll
      for (int mi = 0; mi < 4; ++mi)
        afr[mi] = *(const bf16x8*)&Xs[cq + mi * 16 + lrow][kc];
      #pragma unroll
      for (int ni = 0; ni < 4; ++ni)
        bfr[ni] = *(const bf16x8*)&Ws[nq + ni * 16 + lrow][kc];
      #pragma unroll
      for (int mi = 0; mi < 4; ++mi)
        #pragma unroll
        for (int ni = 0; ni < 4; ++ni)
          acc[mi][ni] = __builtin_amdgcn_mfma_f32_16x16x32_bf16(
              afr[mi], bfr[ni], acc[mi][ni], 0, 0, 0);
    }
  }

  #pragma unroll
  for (int ni = 0; ni < 4; ++ni) {
    const int n = n0 + nq + ni * 16 + lrow;
    float sv = 0.f;
    #pragma unroll
    for (int mi = 0; mi < 4; ++mi) {
      const int cbase = c0 + cq + mi * 16 + lquad * 4;
      #pragma unroll
      for (int i = 0; i < 4; ++i)
        sv += acc[mi][ni][i] * Wd[(size_t)n * C_ + (cbase + i)];
    }
    sv += __shfl_xor(sv, 16, 64);
    sv += __shfl_xor(sv, 32, 64);
    if (lane < 16) {
      if (c_blk == 0 && cq == 0) sv += Wb[n];
      atomicAdd(&out[(size_t)b * N_ + n], sv);
    }
  }
}

extern "C" void kernel_launch(void* const* d_in, const int* in_sizes, int n_in,
                              void* d_out, int out_size, void* d_ws, size_t ws_size,
                              hipStream_t stream) {
  const float* x   = (const float*)d_in[0];   // [512,384,13,13]
  const float* Wsp = (const float*)d_in[1];   // [512,13,13]
  const float* Wd  = (const float*)d_in[2];   // [512,384]
  const float* Wb  = (const float*)d_in[3];   // [1,512]
  float* out = (float*)d_out;                 // [512,512] fp32

  const size_t need_basic = WSF_ELEMS * sizeof(__bf16) + WDF_ELEMS * sizeof(float);
  const size_t need_full  = need_basic + PART_ELEMS * sizeof(float);

  if (ws_size >= need_full) {
    __bf16* wsf  = (__bf16*)d_ws;
    float*  wdf  = (float*)(wsf + WSF_ELEMS);
    float*  partb = wdf + WDF_ELEMS;

    prep_aux_kernel<<<240, 256, 0, stream>>>(Wsp, Wd, wsf, wdf);
    conv_part<<<2048, 256, 0, stream>>>(x, wsf, wdf, partb);
    reduce_part<<<256, 256, 0, stream>>>(partb, Wb, out);
  } else if (ws_size >= need_basic) {
    __bf16* wsf = (__bf16*)d_ws;
    float*  wdf = (float*)(wsf + WSF_ELEMS);

    hipMemsetAsync(d_out, 0, (size_t)out_size * sizeof(float), stream);
    prep_aux_kernel<<<240, 256, 0, stream>>>(Wsp, Wd, wsf, wdf);
    conv_fused_v8<<<1536, 256, 0, stream>>>(x, wsf, wdf, Wb, out);
  } else {
    hipMemsetAsync(d_out, 0, (size_t)out_size * sizeof(float), stream);
    dim3 grid(N_ / NT, C_ / CT, B_);
    conv_main_fallback<<<grid, 256, 0, stream>>>(x, Wsp, Wd, Wb, out);
  }
}

// Round 6
// 264.029 us; speedup vs baseline: 1.5612x; 1.3128x over previous
//
#include <hip/hip_runtime.h>

// out[b,n] = sum_{c,hw} x[b,c,hw] * W_s[n,hw] * W_d[n,c] + W_b[n]
// B=512, C=384, N=512, HW=169 (13x13).
//
// R14 = R13 + the missing cross-wave combine (R13 raced: 4 waves, each owning
// a 32-row c-quarter, overwrote the same pb[n] with quarter-sums).
//  - A-frags persist in registers: a[2][6] per wave, 12 ds_read_b128 ONCE.
//  - nf loop (32 n-frags): 6 bfr global loads (wsf, L1/L2-shared by all
//    waves), 12 MFMA, wdf fold, 2 shfl_xor; lane<16 writes the wave's
//    quarter-sum to red[wv][n] (8 KB aliased over dead Xs).
//  - Barrier discipline: (1) post-staging, (2) post-A-read (makes the red/Xs
//    alias race-free), (3) pre-combine. 256 threads then sum 4 waves x 2 n
//    and plain-store COMPLETE per-(b,c_blk,n) partials to the 3 MB slab.
//  - No atomics (R10 lesson), launch_bounds(256,3) regime (R9/R12 lessons:
//    ",4" = 64-VGPR spill hell; unbounded = 132 VGPR occupancy cliff).

#define B_   512
#define C_   384
#define N_   512
#define HW_  169
#define CT   128     // c-tile rows (3 c_blks per b)
#define SXR  200     // Xs row stride in bf16 (16B-aligned rows)

#define WSF_ELEMS  ((size_t)32 * 6 * 64 * 8)       // 98,304 bf16
#define WDF_ELEMS  ((size_t)24 * 32 * 64 * 4)      // 196,608 f32
#define PART_ELEMS ((size_t)3 * B_ * N_)           // 786,432 f32 (3 MB)

typedef __bf16 bf16x8 __attribute__((ext_vector_type(8)));
typedef float f32x4  __attribute__((ext_vector_type(4)));
typedef float f32x4u __attribute__((ext_vector_type(4), aligned(4)));

__device__ __forceinline__ __bf16 f2bf(float f) {
  union { float f; unsigned u; } v; v.f = f;
  unsigned r = (v.u + 0x7FFFu + ((v.u >> 16) & 1u)) >> 16;   // RNE
  unsigned short s = (unsigned short)r;
  return __builtin_bit_cast(__bf16, s);
}

// hi16(a)|hi16(b)<<16 : two bf16 truncations in one v_perm
__device__ __forceinline__ unsigned pack_trunc(float a, float b) {
  return __builtin_amdgcn_perm(__builtin_bit_cast(unsigned, b),
                               __builtin_bit_cast(unsigned, a), 0x07060302u);
}

// ---------------- prep_aux: wsf (B-frag order) + wdf (C-layout order) ----------------
__global__ __launch_bounds__(256)
void prep_aux_kernel(const float* __restrict__ Ws,
                     const float* __restrict__ Wd,
                     __bf16* __restrict__ wsf,
                     float* __restrict__ wdf) {
  int t = blockIdx.x * 256 + threadIdx.x;      // 61440 total, exact
  if (t < 12288) {
    // wsf: t = (nm*6 + kb)*64 + lane ; lane(q=l>>4,m=l&15) holds Ws[nm*16+m][kb*32+q*8+j]
    int lane = t & 63;
    int fr   = t >> 6;
    int kb   = fr % 6;
    int nm   = fr / 6;
    int n    = nm * 16 + (lane & 15);
    int k0   = kb * 32 + (lane >> 4) * 8;
    const float* src = Ws + (size_t)n * HW_;
    bf16x8 v;
    #pragma unroll
    for (int j = 0; j < 8; ++j) {
      int k = k0 + j;
      float f = (k < HW_) ? src[k] : 0.f;
      v[j] = f2bf(f);
    }
    *(bf16x8*)(wsf + (size_t)t * 8) = v;
  } else {
    // wdf: t2 = (cm*32 + nm)*64 + lane; elem i = Wd[nm*16+(l&15)][cm*16+(l>>4)*4+i]
    int t2 = t - 12288;
    int lane = t2 & 63;
    int fr   = t2 >> 6;
    int nm   = fr & 31;
    int cm   = fr >> 5;
    int n    = nm * 16 + (lane & 15);
    int c0   = cm * 16 + (lane >> 4) * 4;
    f32x4 w = *(const f32x4u*)(Wd + (size_t)n * C_ + c0);
    *(f32x4*)(wdf + (size_t)t2 * 4) = w;
  }
}

// ---------------- R14 main kernel: A-in-registers + LDS cross-wave combine ----------------
__global__ __launch_bounds__(256, 3)       // proven-good register regime
void conv_part(const float* __restrict__ x,
               const __bf16* __restrict__ wsf,
               const float* __restrict__ wdf,
               float* __restrict__ part) {
  __shared__ __align__(16) __bf16 Xs[CT * SXR];   // 51.2 KB; red[] aliases head post-A-read

  const int tid  = threadIdx.x;
  // XCD swizzle: the 3 c_blks of one b land on the same id%8 slot.
  const int id    = blockIdx.x;     // 0..1535
  const int slot  = id & 7;
  const int t8    = id >> 3;        // 0..191
  const int c_blk = t8 % 3;
  const int b     = (t8 / 3) * 8 + slot;

  const int lane  = tid & 63;
  const int wv    = tid >> 6;          // 4 waves; wave owns 32 c-rows (2 frags)
  const int lrow  = lane & 15;
  const int lquad = lane >> 4;

  // ---- stage X tile: 128 rows x 169 cols fp32 -> bf16 (cols padded to 192) ----
  const float* src = x + ((size_t)b * C_ + (size_t)c_blk * CT) * HW_;
  // 128 rows x 48 chunks(4 cols) = 6144 items = 24/thread exact
  #pragma unroll 4
  for (int p = 0; p < 24; ++p) {
    int i   = p * 256 + tid;
    int row = i / 48;
    int ch  = i - row * 48;
    const float* bp = src + row * HW_ + ch * 4;
    float v0 = 0.f, v1 = 0.f, v2 = 0.f, v3 = 0.f;
    if (ch < 42) {                      // cols ch*4..+3 <= 167
      f32x4u t = *(const f32x4u*)bp;
      v0 = t[0]; v1 = t[1]; v2 = t[2]; v3 = t[3];
    } else if (ch == 42) {              // only col 168 valid
      v0 = bp[0];
    }                                    // ch 43..47: zero pad to col 191
    unsigned d0 = pack_trunc(v0, v1);
    unsigned d1 = pack_trunc(v2, v3);
    uint2 d; d.x = d0; d.y = d1;
    *(uint2*)&Xs[row * SXR + ch * 4] = d;
  }
  __syncthreads();   // barrier 1: staging complete

  // ---- A-fragments into persistent registers: 12 ds_read_b128, ONCE ----
  bf16x8 a[2][6];
  #pragma unroll
  for (int mi = 0; mi < 2; ++mi)
    #pragma unroll
    for (int kb = 0; kb < 6; ++kb)
      a[mi][kb] = *(const bf16x8*)&Xs[(wv * 32 + mi * 16 + lrow) * SXR + kb * 32 + lquad * 8];

  __syncthreads();   // barrier 2: all A-reads done -> Xs dead, red alias safe

  float* red = reinterpret_cast<float*>(Xs);   // red[wv][512]: 8 KB of 51.2 KB

  const int cm0 = c_blk * 8 + wv * 2;       // global 16-c fragment row (0..23)
  const __bf16* bb = wsf + (size_t)lane * 8;
  const float*  wb = wdf + (size_t)lane * 4;
  const f32x4 zero = {0.f, 0.f, 0.f, 0.f};

  // ---- 32 n-fragments: stream B from L2, MFMA from registers, fold, red-write ----
  #pragma unroll 2
  for (int nf = 0; nf < 32; ++nf) {
    bf16x8 bfr[6];
    #pragma unroll
    for (int kb = 0; kb < 6; ++kb)
      bfr[kb] = *(const bf16x8*)(bb + ((size_t)nf * 6 + kb) * 512);

    f32x4 acc[2] = {zero, zero};
    #pragma unroll
    for (int kb = 0; kb < 6; ++kb)
      #pragma unroll
      for (int mi = 0; mi < 2; ++mi)
        acc[mi] = __builtin_amdgcn_mfma_f32_16x16x32_bf16(
            a[mi][kb], bfr[kb], acc[mi], 0, 0, 0);

    // fold acc * W_d (wdf C-layout, proven R7/R8 under CT=128)
    float t = 0.f;
    #pragma unroll
    for (int mi = 0; mi < 2; ++mi) {
      const f32x4 w = *(const f32x4*)(wb + (((size_t)(cm0 + mi) * 32 + nf) * 256));
      t += acc[mi][0] * w[0] + acc[mi][1] * w[1]
         + acc[mi][2] * w[2] + acc[mi][3] * w[3];
    }
    // lanes {m,m+16,m+32,m+48} hold disjoint c-slices of the same n
    t += __shfl_xor(t, 16, 64);
    t += __shfl_xor(t, 32, 64);
    if (lane < 16)
      red[wv * 512 + nf * 16 + lrow] = t;   // per-wave c-quarter sum
  }
  __syncthreads();   // barrier 3: all quarter-sums in red

  // ---- cross-wave combine: 256 threads x 2 n -> complete partials, plain store ----
  float* pb = part + ((size_t)c_blk * B_ + b) * N_;
  #pragma unroll
  for (int r = 0; r < 2; ++r) {
    const int n = r * 256 + tid;
    float v = red[n] + red[512 + n] + red[1024 + n] + red[1536 + n];
    pb[n] = v;
  }
}

// ---------------- reducer: out = sum of 3 slabs + bias ----------------
__global__ __launch_bounds__(256)
void reduce_part(const float* __restrict__ part,
                 const float* __restrict__ Wb,
                 float* __restrict__ out) {
  const size_t S = (size_t)B_ * N_;
  int idx = (blockIdx.x * 256 + threadIdx.x) * 4;   // 256 blocks -> covers 262144
  f32x4 a0 = *(const f32x4u*)(part + idx);
  f32x4 a1 = *(const f32x4u*)(part + S + idx);
  f32x4 a2 = *(const f32x4u*)(part + 2 * S + idx);
  f32x4 wb = *(const f32x4u*)(Wb + (idx & (N_ - 1)));
  f32x4 r;
  #pragma unroll
  for (int i = 0; i < 4; ++i)
    r[i] = a0[i] + a1[i] + a2[i] + wb[i];
  *(f32x4*)(out + idx) = r;
}

// ---------------- R8 main kernel (ws fits wsf+wdf only; 110 us proven) ----------------
__global__ __launch_bounds__(256, 3)
void conv_fused_v8(const float* __restrict__ x,
                   const __bf16* __restrict__ wsf,
                   const float* __restrict__ wdf,
                   const float* __restrict__ Wb,
                   float* __restrict__ out) {
  __shared__ __align__(16) __bf16 Xs[CT * SXR];   // 51.2 KB
  __shared__ float red[4][64];                     // 1 KB

  const int tid  = threadIdx.x;
  const int id    = blockIdx.x;     // 0..1535
  const int slot  = id & 7;
  const int t8    = id >> 3;        // 0..191
  const int c_blk = t8 % 3;
  const int b     = (t8 / 3) * 8 + slot;

  const int lane  = tid & 63;
  const int wv    = tid >> 6;          // 4 waves: 2x2 (c,n) 64x64 quadrants
  const int cq    = (wv >> 1) * 64;
  const int nq    = (wv & 1) * 64;
  const int lrow  = lane & 15;
  const int lquad = lane >> 4;

  const float* src = x + ((size_t)b * C_ + (size_t)c_blk * CT) * HW_;
  #pragma unroll 4
  for (int p = 0; p < 24; ++p) {
    int i   = p * 256 + tid;
    int row = i / 48;
    int ch  = i - row * 48;
    const float* bp = src + row * HW_ + ch * 4;
    float v0 = 0.f, v1 = 0.f, v2 = 0.f, v3 = 0.f;
    if (ch < 42) {
      f32x4u t = *(const f32x4u*)bp;
      v0 = t[0]; v1 = t[1]; v2 = t[2]; v3 = t[3];
    } else if (ch == 42) {
      v0 = bp[0];
    }
    unsigned d0 = pack_trunc(v0, v1);
    unsigned d1 = pack_trunc(v2, v3);
    uint2 d; d.x = d0; d.y = d1;
    *(uint2*)&Xs[row * SXR + ch * 4] = d;
  }
  __syncthreads();

  const int cm0 = c_blk * 8 + (cq >> 4);

  #pragma unroll 1
  for (int nb = 0; nb < 4; ++nb) {
    const int nm0 = nb * 8 + (nq >> 4);
    const __bf16* bbase = wsf + ((size_t)nm0 * 6) * 512 + (size_t)lane * 8;

    const f32x4 zero = {0.f, 0.f, 0.f, 0.f};
    f32x4 acc[4][4];
    #pragma unroll
    for (int mi = 0; mi < 4; ++mi)
      #pragma unroll
      for (int ni = 0; ni < 4; ++ni)
        acc[mi][ni] = zero;

    #pragma unroll
    for (int kb = 0; kb < 6; ++kb) {
      bf16x8 afr[4], bfr[4];
      #pragma unroll
      for (int mi = 0; mi < 4; ++mi)
        afr[mi] = *(const bf16x8*)&Xs[(cq + mi * 16 + lrow) * SXR + kb * 32 + lquad * 8];
      #pragma unroll
      for (int ni = 0; ni < 4; ++ni)
        bfr[ni] = *(const bf16x8*)(bbase + ((size_t)ni * 6 + kb) * 512);
      #pragma unroll
      for (int mi = 0; mi < 4; ++mi)
        #pragma unroll
        for (int ni = 0; ni < 4; ++ni)
          acc[mi][ni] = __builtin_amdgcn_mfma_f32_16x16x32_bf16(
              afr[mi], bfr[ni], acc[mi][ni], 0, 0, 0);
    }

    float s[4] = {0.f, 0.f, 0.f, 0.f};
    #pragma unroll
    for (int ni = 0; ni < 4; ++ni) {
      #pragma unroll
      for (int mi = 0; mi < 4; ++mi) {
        const f32x4 w = *(const f32x4*)(wdf +
            (((size_t)(cm0 + mi) * 32 + (nm0 + ni)) * 64 + lane) * 4);
        s[ni] += acc[mi][ni][0] * w[0] + acc[mi][ni][1] * w[1]
               + acc[mi][ni][2] * w[2] + acc[mi][ni][3] * w[3];
      }
    }

    #pragma unroll
    for (int ni = 0; ni < 4; ++ni) {
      s[ni] += __shfl_xor(s[ni], 16, 64);
      s[ni] += __shfl_xor(s[ni], 32, 64);
    }
    if (lane < 16) {
      #pragma unroll
      for (int ni = 0; ni < 4; ++ni)
        red[wv][ni * 16 + lrow] = s[ni];
    }
    __syncthreads();

    if (tid < 128) {
      const int half = tid >> 6;
      const int idx  = tid & 63;
      const int n    = nb * 128 + tid;
      float v = red[half][idx] + red[half + 2][idx];
      if (c_blk == 0) v += Wb[n];
      atomicAdd(&out[(size_t)b * N_ + n], v);
    }
    __syncthreads();
  }
}

// ---------------- fallback main kernel (no workspace needed) ----------------

#define LDSS 104
#define KCH  96
#define NT   128

__global__ __launch_bounds__(256)
void conv_main_fallback(const float* __restrict__ x,
                        const float* __restrict__ Ws_g,
                        const float* __restrict__ Wd,
                        const float* __restrict__ Wb,
                        float* __restrict__ out) {
  __shared__ __align__(16) __bf16 Xs[CT][LDSS];
  __shared__ __align__(16) __bf16 Ws[NT][LDSS];

  const int tid   = threadIdx.x;
  const int n_blk = blockIdx.x;
  const int c_blk = blockIdx.y;
  const int b     = blockIdx.z;
  const int c0 = c_blk * CT;
  const int n0 = n_blk * NT;
  const int lane  = tid & 63;
  const int wv    = tid >> 6;
  const int cq    = (wv >> 1) * 64;
  const int nq    = (wv & 1) * 64;
  const int lrow  = lane & 15;
  const int lquad = lane >> 4;

  const f32x4 zero = {0.f, 0.f, 0.f, 0.f};
  f32x4 acc[4][4];
  #pragma unroll
  for (int mi = 0; mi < 4; ++mi)
    #pragma unroll
    for (int ni = 0; ni < 4; ++ni)
      acc[mi][ni] = zero;

  const float* xb  = x    + (size_t)b  * (C_ * HW_) + (size_t)c0 * HW_;
  const float* wsb = Ws_g + (size_t)n0 * HW_;

  for (int ch = 0; ch < 2; ++ch) {
    const int k0 = ch * KCH;
    __syncthreads();
    for (int e = tid; e < CT * KCH; e += 256) {
      int r   = e / KCH;
      int col = e - r * KCH;
      int k   = k0 + col;
      float vx = 0.f, vw = 0.f;
      if (k < HW_) {
        vx = xb [r * HW_ + k];
        vw = wsb[r * HW_ + k];
      }
      Xs[r][col] = f2bf(vx);
      Ws[r][col] = f2bf(vw);
    }
    __syncthreads();

    #pragma unroll
    for (int ks = 0; ks < 3; ++ks) {
      const int kc = ks * 32 + lquad * 8;
      bf16x8 afr[4], bfr[4];
      #pragma unroll
      for (int mi = 0; mi < 4; ++mi)
        afr[mi] = *(const bf16x8*)&Xs[cq + mi * 16 + lrow][kc];
      #pragma unroll
      for (int ni = 0; ni < 4; ++ni)
        bfr[ni] = *(const bf16x8*)&Ws[nq + ni * 16 + lrow][kc];
      #pragma unroll
      for (int mi = 0; mi < 4; ++mi)
        #pragma unroll
        for (int ni = 0; ni < 4; ++ni)
          acc[mi][ni] = __builtin_amdgcn_mfma_f32_16x16x32_bf16(
              afr[mi], bfr[ni], acc[mi][ni], 0, 0, 0);
    }
  }

  #pragma unroll
  for (int ni = 0; ni < 4; ++ni) {
    const int n = n0 + nq + ni * 16 + lrow;
    float sv = 0.f;
    #pragma unroll
    for (int mi = 0; mi < 4; ++mi) {
      const int cbase = c0 + cq + mi * 16 + lquad * 4;
      #pragma unroll
      for (int i = 0; i < 4; ++i)
        sv += acc[mi][ni][i] * Wd[(size_t)n * C_ + (cbase + i)];
    }
    sv += __shfl_xor(sv, 16, 64);
    sv += __shfl_xor(sv, 32, 64);
    if (lane < 16) {
      if (c_blk == 0 && cq == 0) sv += Wb[n];
      atomicAdd(&out[(size_t)b * N_ + n], sv);
    }
  }
}

extern "C" void kernel_launch(void* const* d_in, const int* in_sizes, int n_in,
                              void* d_out, int out_size, void* d_ws, size_t ws_size,
                              hipStream_t stream) {
  const float* x   = (const float*)d_in[0];   // [512,384,13,13]
  const float* Wsp = (const float*)d_in[1];   // [512,13,13]
  const float* Wd  = (const float*)d_in[2];   // [512,384]
  const float* Wb  = (const float*)d_in[3];   // [1,512]
  float* out = (float*)d_out;                 // [512,512] fp32

  const size_t need_basic = WSF_ELEMS * sizeof(__bf16) + WDF_ELEMS * sizeof(float);
  const size_t need_full  = need_basic + PART_ELEMS * sizeof(float);

  if (ws_size >= need_full) {
    __bf16* wsf  = (__bf16*)d_ws;
    float*  wdf  = (float*)(wsf + WSF_ELEMS);
    float*  partb = wdf + WDF_ELEMS;

    prep_aux_kernel<<<240, 256, 0, stream>>>(Wsp, Wd, wsf, wdf);
    conv_part<<<1536, 256, 0, stream>>>(x, wsf, wdf, partb);
    reduce_part<<<256, 256, 0, stream>>>(partb, Wb, out);
  } else if (ws_size >= need_basic) {
    __bf16* wsf = (__bf16*)d_ws;
    float*  wdf = (float*)(wsf + WSF_ELEMS);

    hipMemsetAsync(d_out, 0, (size_t)out_size * sizeof(float), stream);
    prep_aux_kernel<<<240, 256, 0, stream>>>(Wsp, Wd, wsf, wdf);
    conv_fused_v8<<<1536, 256, 0, stream>>>(x, wsf, wdf, Wb, out);
  } else {
    hipMemsetAsync(d_out, 0, (size_t)out_size * sizeof(float), stream);
    dim3 grid(N_ / NT, C_ / CT, B_);
    conv_main_fallback<<<grid, 256, 0, stream>>>(x, Wsp, Wd, Wb, out);
  }
}

// Round 7
// 254.420 us; speedup vs baseline: 1.6202x; 1.0378x over previous
//
#include <hip/hip_runtime.h>

// out[b,n] = sum_{c,hw} x[b,c,hw] * W_s[n,hw] * W_d[n,c] + W_b[n]
// B=512, C=384, N=512, HW=169 (13x13).
//
// R15 = R14 minus the LDS staging relay. R14 counters: correct, no spill,
// but 33% occupancy (51.2 KB Xs -> 3 blocks/CU) and all pipes <14% busy =
// latency-bound. The Xs relay only existed to hand each wave its own 32
// c-rows — which it can load DIRECTLY from global (16 rows x 4 contiguous
// 32B chunks per instruction = 128B segments, same 24 loads/thread as the
// staging loop), packing fp32->bf16 in registers (4 v_perm per frag, once).
//  - LDS: 8 KB red[] only. Barriers: 1 (pre-combine).
//  - Occupancy cap moves to VGPR (~100 est, (256,3) budget 170):
//    ~5 waves/SIMD vs 2.6 -> ~2x latency hiding.
//  - Everything proven stays: wsf B-frag stream, wdf C-layout fold,
//    quad-shfl, cross-wave red combine, 3-slab part + tiny reducer,
//    no atomics, XCD swizzle.

#define B_   512
#define C_   384
#define N_   512
#define HW_  169
#define CT   128     // c-tile rows (3 c_blks per b)
#define SXR  200     // Xs row stride (v8/fallback kernels)

#define WSF_ELEMS  ((size_t)32 * 6 * 64 * 8)       // 98,304 bf16
#define WDF_ELEMS  ((size_t)24 * 32 * 64 * 4)      // 196,608 f32
#define PART_ELEMS ((size_t)3 * B_ * N_)           // 786,432 f32 (3 MB)

typedef __bf16 bf16x8 __attribute__((ext_vector_type(8)));
typedef float f32x4  __attribute__((ext_vector_type(4)));
typedef float f32x4u __attribute__((ext_vector_type(4), aligned(4)));
typedef unsigned u32x4 __attribute__((ext_vector_type(4)));

__device__ __forceinline__ __bf16 f2bf(float f) {
  union { float f; unsigned u; } v; v.f = f;
  unsigned r = (v.u + 0x7FFFu + ((v.u >> 16) & 1u)) >> 16;   // RNE
  unsigned short s = (unsigned short)r;
  return __builtin_bit_cast(__bf16, s);
}

// hi16(a)|hi16(b)<<16 : two bf16 truncations in one v_perm
__device__ __forceinline__ unsigned pack_trunc(float a, float b) {
  return __builtin_amdgcn_perm(__builtin_bit_cast(unsigned, b),
                               __builtin_bit_cast(unsigned, a), 0x07060302u);
}

// ---------------- prep_aux: wsf (B-frag order) + wdf (C-layout order) ----------------
__global__ __launch_bounds__(256)
void prep_aux_kernel(const float* __restrict__ Ws,
                     const float* __restrict__ Wd,
                     __bf16* __restrict__ wsf,
                     float* __restrict__ wdf) {
  int t = blockIdx.x * 256 + threadIdx.x;      // 61440 total, exact
  if (t < 12288) {
    // wsf: t = (nm*6 + kb)*64 + lane ; lane(q=l>>4,m=l&15) holds Ws[nm*16+m][kb*32+q*8+j]
    int lane = t & 63;
    int fr   = t >> 6;
    int kb   = fr % 6;
    int nm   = fr / 6;
    int n    = nm * 16 + (lane & 15);
    int k0   = kb * 32 + (lane >> 4) * 8;
    const float* src = Ws + (size_t)n * HW_;
    bf16x8 v;
    #pragma unroll
    for (int j = 0; j < 8; ++j) {
      int k = k0 + j;
      float f = (k < HW_) ? src[k] : 0.f;
      v[j] = f2bf(f);
    }
    *(bf16x8*)(wsf + (size_t)t * 8) = v;
  } else {
    // wdf: t2 = (cm*32 + nm)*64 + lane; elem i = Wd[nm*16+(l&15)][cm*16+(l>>4)*4+i]
    int t2 = t - 12288;
    int lane = t2 & 63;
    int fr   = t2 >> 6;
    int nm   = fr & 31;
    int cm   = fr >> 5;
    int n    = nm * 16 + (lane & 15);
    int c0   = cm * 16 + (lane >> 4) * 4;
    f32x4 w = *(const f32x4u*)(Wd + (size_t)n * C_ + c0);
    *(f32x4*)(wdf + (size_t)t2 * 4) = w;
  }
}

// ---------------- R15 main kernel: direct A-load, no staging, 1 barrier ----------------
__global__ __launch_bounds__(256, 3)       // proven-good register regime
void conv_part(const float* __restrict__ x,
               const __bf16* __restrict__ wsf,
               const float* __restrict__ wdf,
               float* __restrict__ part) {
  __shared__ float red[4 * 512];            // 8 KB — the ONLY LDS

  const int tid  = threadIdx.x;
  // XCD swizzle: the 3 c_blks of one b land on the same id%8 slot.
  const int id    = blockIdx.x;     // 0..1535
  const int slot  = id & 7;
  const int t8    = id >> 3;        // 0..191
  const int c_blk = t8 % 3;
  const int b     = (t8 / 3) * 8 + slot;

  const int lane  = tid & 63;
  const int wv    = tid >> 6;          // 4 waves; wave owns 32 c-rows (2 frags)
  const int lrow  = lane & 15;
  const int lquad = lane >> 4;

  // ---- A-fragments DIRECT from global: 12 frags, f32x4 pairs, pack in-reg ----
  bf16x8 a[2][6];
  #pragma unroll
  for (int mi = 0; mi < 2; ++mi) {
    const float* rp = x + ((size_t)b * C_ + (size_t)c_blk * CT + wv * 32 + mi * 16 + lrow) * HW_;
    #pragma unroll
    for (int kb = 0; kb < 6; ++kb) {
      const int k0 = kb * 32 + lquad * 8;
      float v0, v1, v2, v3, v4, v5, v6, v7;
      if (kb < 5 || k0 + 7 < HW_) {          // kb<=4 always safe (max 159)
        f32x4u t0 = *(const f32x4u*)(rp + k0);
        f32x4u t1 = *(const f32x4u*)(rp + k0 + 4);
        v0 = t0[0]; v1 = t0[1]; v2 = t0[2]; v3 = t0[3];
        v4 = t1[0]; v5 = t1[1]; v6 = t1[2]; v7 = t1[3];
      } else {                               // kb==5 tail: cols 168.. mostly pad
        v0 = (k0 + 0 < HW_) ? rp[k0 + 0] : 0.f;
        v1 = v2 = v3 = v4 = v5 = v6 = v7 = 0.f;
      }
      u32x4 pk;
      pk.x = pack_trunc(v0, v1);
      pk.y = pack_trunc(v2, v3);
      pk.z = pack_trunc(v4, v5);
      pk.w = pack_trunc(v6, v7);
      a[mi][kb] = __builtin_bit_cast(bf16x8, pk);
    }
  }

  const int cm0 = c_blk * 8 + wv * 2;       // global 16-c fragment row (0..23)
  const __bf16* bb = wsf + (size_t)lane * 8;
  const float*  wb = wdf + (size_t)lane * 4;
  const f32x4 zero = {0.f, 0.f, 0.f, 0.f};

  // ---- 32 n-fragments: stream B from L2, MFMA from registers, fold, red-write ----
  #pragma unroll 2
  for (int nf = 0; nf < 32; ++nf) {
    bf16x8 bfr[6];
    #pragma unroll
    for (int kb = 0; kb < 6; ++kb)
      bfr[kb] = *(const bf16x8*)(bb + ((size_t)nf * 6 + kb) * 512);

    f32x4 acc[2] = {zero, zero};
    #pragma unroll
    for (int kb = 0; kb < 6; ++kb)
      #pragma unroll
      for (int mi = 0; mi < 2; ++mi)
        acc[mi] = __builtin_amdgcn_mfma_f32_16x16x32_bf16(
            a[mi][kb], bfr[kb], acc[mi], 0, 0, 0);

    // fold acc * W_d (wdf C-layout, proven R7/R8 under CT=128)
    float t = 0.f;
    #pragma unroll
    for (int mi = 0; mi < 2; ++mi) {
      const f32x4 w = *(const f32x4*)(wb + (((size_t)(cm0 + mi) * 32 + nf) * 256));
      t += acc[mi][0] * w[0] + acc[mi][1] * w[1]
         + acc[mi][2] * w[2] + acc[mi][3] * w[3];
    }
    // lanes {m,m+16,m+32,m+48} hold disjoint c-slices of the same n
    t += __shfl_xor(t, 16, 64);
    t += __shfl_xor(t, 32, 64);
    if (lane < 16)
      red[wv * 512 + nf * 16 + lrow] = t;   // per-wave c-quarter sum
  }
  __syncthreads();   // the ONLY barrier

  // ---- cross-wave combine: 256 threads x 2 n -> complete partials, plain store ----
  float* pb = part + ((size_t)c_blk * B_ + b) * N_;
  #pragma unroll
  for (int r = 0; r < 2; ++r) {
    const int n = r * 256 + tid;
    float v = red[n] + red[512 + n] + red[1024 + n] + red[1536 + n];
    pb[n] = v;
  }
}

// ---------------- reducer: out = sum of 3 slabs + bias ----------------
__global__ __launch_bounds__(256)
void reduce_part(const float* __restrict__ part,
                 const float* __restrict__ Wb,
                 float* __restrict__ out) {
  const size_t S = (size_t)B_ * N_;
  int idx = (blockIdx.x * 256 + threadIdx.x) * 4;   // 256 blocks -> covers 262144
  f32x4 a0 = *(const f32x4u*)(part + idx);
  f32x4 a1 = *(const f32x4u*)(part + S + idx);
  f32x4 a2 = *(const f32x4u*)(part + 2 * S + idx);
  f32x4 wb = *(const f32x4u*)(Wb + (idx & (N_ - 1)));
  f32x4 r;
  #pragma unroll
  for (int i = 0; i < 4; ++i)
    r[i] = a0[i] + a1[i] + a2[i] + wb[i];
  *(f32x4*)(out + idx) = r;
}

// ---------------- R8 main kernel (ws fits wsf+wdf only; 110 us proven) ----------------
__global__ __launch_bounds__(256, 3)
void conv_fused_v8(const float* __restrict__ x,
                   const __bf16* __restrict__ wsf,
                   const float* __restrict__ wdf,
                   const float* __restrict__ Wb,
                   float* __restrict__ out) {
  __shared__ __align__(16) __bf16 Xs[CT * SXR];   // 51.2 KB
  __shared__ float red[4][64];                     // 1 KB

  const int tid  = threadIdx.x;
  const int id    = blockIdx.x;     // 0..1535
  const int slot  = id & 7;
  const int t8    = id >> 3;        // 0..191
  const int c_blk = t8 % 3;
  const int b     = (t8 / 3) * 8 + slot;

  const int lane  = tid & 63;
  const int wv    = tid >> 6;          // 4 waves: 2x2 (c,n) 64x64 quadrants
  const int cq    = (wv >> 1) * 64;
  const int nq    = (wv & 1) * 64;
  const int lrow  = lane & 15;
  const int lquad = lane >> 4;

  const float* src = x + ((size_t)b * C_ + (size_t)c_blk * CT) * HW_;
  #pragma unroll 4
  for (int p = 0; p < 24; ++p) {
    int i   = p * 256 + tid;
    int row = i / 48;
    int ch  = i - row * 48;
    const float* bp = src + row * HW_ + ch * 4;
    float v0 = 0.f, v1 = 0.f, v2 = 0.f, v3 = 0.f;
    if (ch < 42) {
      f32x4u t = *(const f32x4u*)bp;
      v0 = t[0]; v1 = t[1]; v2 = t[2]; v3 = t[3];
    } else if (ch == 42) {
      v0 = bp[0];
    }
    unsigned d0 = pack_trunc(v0, v1);
    unsigned d1 = pack_trunc(v2, v3);
    uint2 d; d.x = d0; d.y = d1;
    *(uint2*)&Xs[row * SXR + ch * 4] = d;
  }
  __syncthreads();

  const int cm0 = c_blk * 8 + (cq >> 4);

  #pragma unroll 1
  for (int nb = 0; nb < 4; ++nb) {
    const int nm0 = nb * 8 + (nq >> 4);
    const __bf16* bbase = wsf + ((size_t)nm0 * 6) * 512 + (size_t)lane * 8;

    const f32x4 zero = {0.f, 0.f, 0.f, 0.f};
    f32x4 acc[4][4];
    #pragma unroll
    for (int mi = 0; mi < 4; ++mi)
      #pragma unroll
      for (int ni = 0; ni < 4; ++ni)
        acc[mi][ni] = zero;

    #pragma unroll
    for (int kb = 0; kb < 6; ++kb) {
      bf16x8 afr[4], bfr[4];
      #pragma unroll
      for (int mi = 0; mi < 4; ++mi)
        afr[mi] = *(const bf16x8*)&Xs[(cq + mi * 16 + lrow) * SXR + kb * 32 + lquad * 8];
      #pragma unroll
      for (int ni = 0; ni < 4; ++ni)
        bfr[ni] = *(const bf16x8*)(bbase + ((size_t)ni * 6 + kb) * 512);
      #pragma unroll
      for (int mi = 0; mi < 4; ++mi)
        #pragma unroll
        for (int ni = 0; ni < 4; ++ni)
          acc[mi][ni] = __builtin_amdgcn_mfma_f32_16x16x32_bf16(
              afr[mi], bfr[ni], acc[mi][ni], 0, 0, 0);
    }

    float s[4] = {0.f, 0.f, 0.f, 0.f};
    #pragma unroll
    for (int ni = 0; ni < 4; ++ni) {
      #pragma unroll
      for (int mi = 0; mi < 4; ++mi) {
        const f32x4 w = *(const f32x4*)(wdf +
            (((size_t)(cm0 + mi) * 32 + (nm0 + ni)) * 64 + lane) * 4);
        s[ni] += acc[mi][ni][0] * w[0] + acc[mi][ni][1] * w[1]
               + acc[mi][ni][2] * w[2] + acc[mi][ni][3] * w[3];
      }
    }

    #pragma unroll
    for (int ni = 0; ni < 4; ++ni) {
      s[ni] += __shfl_xor(s[ni], 16, 64);
      s[ni] += __shfl_xor(s[ni], 32, 64);
    }
    if (lane < 16) {
      #pragma unroll
      for (int ni = 0; ni < 4; ++ni)
        red[wv][ni * 16 + lrow] = s[ni];
    }
    __syncthreads();

    if (tid < 128) {
      const int half = tid >> 6;
      const int idx  = tid & 63;
      const int n    = nb * 128 + tid;
      float v = red[half][idx] + red[half + 2][idx];
      if (c_blk == 0) v += Wb[n];
      atomicAdd(&out[(size_t)b * N_ + n], v);
    }
    __syncthreads();
  }
}

// ---------------- fallback main kernel (no workspace needed) ----------------

#define LDSS 104
#define KCH  96
#define NT   128

__global__ __launch_bounds__(256)
void conv_main_fallback(const float* __restrict__ x,
                        const float* __restrict__ Ws_g,
                        const float* __restrict__ Wd,
                        const float* __restrict__ Wb,
                        float* __restrict__ out) {
  __shared__ __align__(16) __bf16 Xs[CT][LDSS];
  __shared__ __align__(16) __bf16 Ws[NT][LDSS];

  const int tid   = threadIdx.x;
  const int n_blk = blockIdx.x;
  const int c_blk = blockIdx.y;
  const int b     = blockIdx.z;
  const int c0 = c_blk * CT;
  const int n0 = n_blk * NT;
  const int lane  = tid & 63;
  const int wv    = tid >> 6;
  const int cq    = (wv >> 1) * 64;
  const int nq    = (wv & 1) * 64;
  const int lrow  = lane & 15;
  const int lquad = lane >> 4;

  const f32x4 zero = {0.f, 0.f, 0.f, 0.f};
  f32x4 acc[4][4];
  #pragma unroll
  for (int mi = 0; mi < 4; ++mi)
    #pragma unroll
    for (int ni = 0; ni < 4; ++ni)
      acc[mi][ni] = zero;

  const float* xb  = x    + (size_t)b  * (C_ * HW_) + (size_t)c0 * HW_;
  const float* wsb = Ws_g + (size_t)n0 * HW_;

  for (int ch = 0; ch < 2; ++ch) {
    const int k0 = ch * KCH;
    __syncthreads();
    for (int e = tid; e < CT * KCH; e += 256) {
      int r   = e / KCH;
      int col = e - r * KCH;
      int k   = k0 + col;
      float vx = 0.f, vw = 0.f;
      if (k < HW_) {
        vx = xb [r * HW_ + k];
        vw = wsb[r * HW_ + k];
      }
      Xs[r][col] = f2bf(vx);
      Ws[r][col] = f2bf(vw);
    }
    __syncthreads();

    #pragma unroll
    for (int ks = 0; ks < 3; ++ks) {
      const int kc = ks * 32 + lquad * 8;
      bf16x8 afr[4], bfr[4];
      #pragma unroll
      for (int mi = 0; mi < 4; ++mi)
        afr[mi] = *(const bf16x8*)&Xs[cq + mi * 16 + lrow][kc];
      #pragma unroll
      for (int ni = 0; ni < 4; ++ni)
        bfr[ni] = *(const bf16x8*)&Ws[nq + ni * 16 + lrow][kc];
      #pragma unroll
      for (int mi = 0; mi < 4; ++mi)
        #pragma unroll
        for (int ni = 0; ni < 4; ++ni)
          acc[mi][ni] = __builtin_amdgcn_mfma_f32_16x16x32_bf16(
              afr[mi], bfr[ni], acc[mi][ni], 0, 0, 0);
    }
  }

  #pragma unroll
  for (int ni = 0; ni < 4; ++ni) {
    const int n = n0 + nq + ni * 16 + lrow;
    float sv = 0.f;
    #pragma unroll
    for (int mi = 0; mi < 4; ++mi) {
      const int cbase = c0 + cq + mi * 16 + lquad * 4;
      #pragma unroll
      for (int i = 0; i < 4; ++i)
        sv += acc[mi][ni][i] * Wd[(size_t)n * C_ + (cbase + i)];
    }
    sv += __shfl_xor(sv, 16, 64);
    sv += __shfl_xor(sv, 32, 64);
    if (lane < 16) {
      if (c_blk == 0 && cq == 0) sv += Wb[n];
      atomicAdd(&out[(size_t)b * N_ + n], sv);
    }
  }
}

extern "C" void kernel_launch(void* const* d_in, const int* in_sizes, int n_in,
                              void* d_out, int out_size, void* d_ws, size_t ws_size,
                              hipStream_t stream) {
  const float* x   = (const float*)d_in[0];   // [512,384,13,13]
  const float* Wsp = (const float*)d_in[1];   // [512,13,13]
  const float* Wd  = (const float*)d_in[2];   // [512,384]
  const float* Wb  = (const float*)d_in[3];   // [1,512]
  float* out = (float*)d_out;                 // [512,512] fp32

  const size_t need_basic = WSF_ELEMS * sizeof(__bf16) + WDF_ELEMS * sizeof(float);
  const size_t need_full  = need_basic + PART_ELEMS * sizeof(float);

  if (ws_size >= need_full) {
    __bf16* wsf  = (__bf16*)d_ws;
    float*  wdf  = (float*)(wsf + WSF_ELEMS);
    float*  partb = wdf + WDF_ELEMS;

    prep_aux_kernel<<<240, 256, 0, stream>>>(Wsp, Wd, wsf, wdf);
    conv_part<<<1536, 256, 0, stream>>>(x, wsf, wdf, partb);
    reduce_part<<<256, 256, 0, stream>>>(partb, Wb, out);
  } else if (ws_size >= need_basic) {
    __bf16* wsf = (__bf16*)d_ws;
    float*  wdf = (float*)(wsf + WSF_ELEMS);

    hipMemsetAsync(d_out, 0, (size_t)out_size * sizeof(float), stream);
    prep_aux_kernel<<<240, 256, 0, stream>>>(Wsp, Wd, wsf, wdf);
    conv_fused_v8<<<1536, 256, 0, stream>>>(x, wsf, wdf, Wb, out);
  } else {
    hipMemsetAsync(d_out, 0, (size_t)out_size * sizeof(float), stream);
    dim3 grid(N_ / NT, C_ / CT, B_);
    conv_main_fallback<<<grid, 256, 0, stream>>>(x, Wsp, Wd, Wb, out);
  }
}

// Round 8
// 249.135 us; speedup vs baseline: 1.6546x; 1.0212x over previous
//
#include <hip/hip_runtime.h>

// out[b,n] = sum_{c,hw} x[b,c,hw] * W_s[n,hw] * W_d[n,c] + W_b[n]
// B=512, C=384, N=512, HW=169 (13x13).
//
// R16 = R15 with the register BAND changed, nothing else.
// R15 post-mortem: correct, zero bank conflicts, WRITE=3MB (no spill), but
// occupancy pinned at ~36% = 3 waves/SIMD: under (256,3) the allocator
// targets the 170-reg band, so total (VGPR+AGPR unified) lands in (128,170].
// R15's steady state is small: a[2][6]=48 (AGPR, MFMA-only) + acc 8 (AGPR)
// + bfr 24 + wdf 8 + addressing ~20 (arch) -> ~50/56 fits the 64/64 split
// of the 128 band. R9-R11 spilled under ",4" because their live state was
// genuinely >128 (merged epilogues, staging buffers) — not because of the
// arg itself.
// Changes vs R15: __launch_bounds__(256,4); nf-loop unroll 2 -> 1 (minimize
// live state; TLP at 4 waves/SIMD replaces ILP).
// Verification: WRITE_SIZE must stay ~3MB (spill detector); Occupancy ~48%.

#define B_   512
#define C_   384
#define N_   512
#define HW_  169
#define CT   128     // c-tile rows (3 c_blks per b)
#define SXR  200     // Xs row stride (v8/fallback kernels)

#define WSF_ELEMS  ((size_t)32 * 6 * 64 * 8)       // 98,304 bf16
#define WDF_ELEMS  ((size_t)24 * 32 * 64 * 4)      // 196,608 f32
#define PART_ELEMS ((size_t)3 * B_ * N_)           // 786,432 f32 (3 MB)

typedef __bf16 bf16x8 __attribute__((ext_vector_type(8)));
typedef float f32x4  __attribute__((ext_vector_type(4)));
typedef float f32x4u __attribute__((ext_vector_type(4), aligned(4)));
typedef unsigned u32x4 __attribute__((ext_vector_type(4)));

__device__ __forceinline__ __bf16 f2bf(float f) {
  union { float f; unsigned u; } v; v.f = f;
  unsigned r = (v.u + 0x7FFFu + ((v.u >> 16) & 1u)) >> 16;   // RNE
  unsigned short s = (unsigned short)r;
  return __builtin_bit_cast(__bf16, s);
}

// hi16(a)|hi16(b)<<16 : two bf16 truncations in one v_perm
__device__ __forceinline__ unsigned pack_trunc(float a, float b) {
  return __builtin_amdgcn_perm(__builtin_bit_cast(unsigned, b),
                               __builtin_bit_cast(unsigned, a), 0x07060302u);
}

// ---------------- prep_aux: wsf (B-frag order) + wdf (C-layout order) ----------------
__global__ __launch_bounds__(256)
void prep_aux_kernel(const float* __restrict__ Ws,
                     const float* __restrict__ Wd,
                     __bf16* __restrict__ wsf,
                     float* __restrict__ wdf) {
  int t = blockIdx.x * 256 + threadIdx.x;      // 61440 total, exact
  if (t < 12288) {
    // wsf: t = (nm*6 + kb)*64 + lane ; lane(q=l>>4,m=l&15) holds Ws[nm*16+m][kb*32+q*8+j]
    int lane = t & 63;
    int fr   = t >> 6;
    int kb   = fr % 6;
    int nm   = fr / 6;
    int n    = nm * 16 + (lane & 15);
    int k0   = kb * 32 + (lane >> 4) * 8;
    const float* src = Ws + (size_t)n * HW_;
    bf16x8 v;
    #pragma unroll
    for (int j = 0; j < 8; ++j) {
      int k = k0 + j;
      float f = (k < HW_) ? src[k] : 0.f;
      v[j] = f2bf(f);
    }
    *(bf16x8*)(wsf + (size_t)t * 8) = v;
  } else {
    // wdf: t2 = (cm*32 + nm)*64 + lane; elem i = Wd[nm*16+(l&15)][cm*16+(l>>4)*4+i]
    int t2 = t - 12288;
    int lane = t2 & 63;
    int fr   = t2 >> 6;
    int nm   = fr & 31;
    int cm   = fr >> 5;
    int n    = nm * 16 + (lane & 15);
    int c0   = cm * 16 + (lane >> 4) * 4;
    f32x4 w = *(const f32x4u*)(Wd + (size_t)n * C_ + c0);
    *(f32x4*)(wdf + (size_t)t2 * 4) = w;
  }
}

// ---------------- R16 main kernel: direct A-load, 4-waves/SIMD register band ----------------
__global__ __launch_bounds__(256, 4)       // fit the 128-total band: 4 waves/SIMD
void conv_part(const float* __restrict__ x,
               const __bf16* __restrict__ wsf,
               const float* __restrict__ wdf,
               float* __restrict__ part) {
  __shared__ float red[4 * 512];            // 8 KB — the ONLY LDS

  const int tid  = threadIdx.x;
  // XCD swizzle: the 3 c_blks of one b land on the same id%8 slot.
  const int id    = blockIdx.x;     // 0..1535
  const int slot  = id & 7;
  const int t8    = id >> 3;        // 0..191
  const int c_blk = t8 % 3;
  const int b     = (t8 / 3) * 8 + slot;

  const int lane  = tid & 63;
  const int wv    = tid >> 6;          // 4 waves; wave owns 32 c-rows (2 frags)
  const int lrow  = lane & 15;
  const int lquad = lane >> 4;

  // ---- A-fragments DIRECT from global: 12 frags, f32x4 pairs, pack in-reg ----
  bf16x8 a[2][6];
  #pragma unroll
  for (int mi = 0; mi < 2; ++mi) {
    const float* rp = x + ((size_t)b * C_ + (size_t)c_blk * CT + wv * 32 + mi * 16 + lrow) * HW_;
    #pragma unroll
    for (int kb = 0; kb < 6; ++kb) {
      const int k0 = kb * 32 + lquad * 8;
      float v0, v1, v2, v3, v4, v5, v6, v7;
      if (kb < 5 || k0 + 7 < HW_) {          // kb<=4 always safe (max 159)
        f32x4u t0 = *(const f32x4u*)(rp + k0);
        f32x4u t1 = *(const f32x4u*)(rp + k0 + 4);
        v0 = t0[0]; v1 = t0[1]; v2 = t0[2]; v3 = t0[3];
        v4 = t1[0]; v5 = t1[1]; v6 = t1[2]; v7 = t1[3];
      } else {                               // kb==5 tail: cols 168.. mostly pad
        v0 = (k0 + 0 < HW_) ? rp[k0 + 0] : 0.f;
        v1 = v2 = v3 = v4 = v5 = v6 = v7 = 0.f;
      }
      u32x4 pk;
      pk.x = pack_trunc(v0, v1);
      pk.y = pack_trunc(v2, v3);
      pk.z = pack_trunc(v4, v5);
      pk.w = pack_trunc(v6, v7);
      a[mi][kb] = __builtin_bit_cast(bf16x8, pk);
    }
  }

  const int cm0 = c_blk * 8 + wv * 2;       // global 16-c fragment row (0..23)
  const __bf16* bb = wsf + (size_t)lane * 8;
  const float*  wb = wdf + (size_t)lane * 4;
  const f32x4 zero = {0.f, 0.f, 0.f, 0.f};

  // ---- 32 n-fragments: stream B from L2, MFMA from registers, fold, red-write ----
  #pragma unroll 1
  for (int nf = 0; nf < 32; ++nf) {
    bf16x8 bfr[6];
    #pragma unroll
    for (int kb = 0; kb < 6; ++kb)
      bfr[kb] = *(const bf16x8*)(bb + ((size_t)nf * 6 + kb) * 512);

    f32x4 acc[2] = {zero, zero};
    #pragma unroll
    for (int kb = 0; kb < 6; ++kb)
      #pragma unroll
      for (int mi = 0; mi < 2; ++mi)
        acc[mi] = __builtin_amdgcn_mfma_f32_16x16x32_bf16(
            a[mi][kb], bfr[kb], acc[mi], 0, 0, 0);

    // fold acc * W_d (wdf C-layout, proven R7/R8 under CT=128)
    float t = 0.f;
    #pragma unroll
    for (int mi = 0; mi < 2; ++mi) {
      const f32x4 w = *(const f32x4*)(wb + (((size_t)(cm0 + mi) * 32 + nf) * 256));
      t += acc[mi][0] * w[0] + acc[mi][1] * w[1]
         + acc[mi][2] * w[2] + acc[mi][3] * w[3];
    }
    // lanes {m,m+16,m+32,m+48} hold disjoint c-slices of the same n
    t += __shfl_xor(t, 16, 64);
    t += __shfl_xor(t, 32, 64);
    if (lane < 16)
      red[wv * 512 + nf * 16 + lrow] = t;   // per-wave c-quarter sum
  }
  __syncthreads();   // the ONLY barrier

  // ---- cross-wave combine: 256 threads x 2 n -> complete partials, plain store ----
  float* pb = part + ((size_t)c_blk * B_ + b) * N_;
  #pragma unroll
  for (int r = 0; r < 2; ++r) {
    const int n = r * 256 + tid;
    float v = red[n] + red[512 + n] + red[1024 + n] + red[1536 + n];
    pb[n] = v;
  }
}

// ---------------- reducer: out = sum of 3 slabs + bias ----------------
__global__ __launch_bounds__(256)
void reduce_part(const float* __restrict__ part,
                 const float* __restrict__ Wb,
                 float* __restrict__ out) {
  const size_t S = (size_t)B_ * N_;
  int idx = (blockIdx.x * 256 + threadIdx.x) * 4;   // 256 blocks -> covers 262144
  f32x4 a0 = *(const f32x4u*)(part + idx);
  f32x4 a1 = *(const f32x4u*)(part + S + idx);
  f32x4 a2 = *(const f32x4u*)(part + 2 * S + idx);
  f32x4 wb = *(const f32x4u*)(Wb + (idx & (N_ - 1)));
  f32x4 r;
  #pragma unroll
  for (int i = 0; i < 4; ++i)
    r[i] = a0[i] + a1[i] + a2[i] + wb[i];
  *(f32x4*)(out + idx) = r;
}

// ---------------- R8 main kernel (ws fits wsf+wdf only; 110 us proven) ----------------
__global__ __launch_bounds__(256, 3)
void conv_fused_v8(const float* __restrict__ x,
                   const __bf16* __restrict__ wsf,
                   const float* __restrict__ wdf,
                   const float* __restrict__ Wb,
                   float* __restrict__ out) {
  __shared__ __align__(16) __bf16 Xs[CT * SXR];   // 51.2 KB
  __shared__ float red[4][64];                     // 1 KB

  const int tid  = threadIdx.x;
  const int id    = blockIdx.x;     // 0..1535
  const int slot  = id & 7;
  const int t8    = id >> 3;        // 0..191
  const int c_blk = t8 % 3;
  const int b     = (t8 / 3) * 8 + slot;

  const int lane  = tid & 63;
  const int wv    = tid >> 6;          // 4 waves: 2x2 (c,n) 64x64 quadrants
  const int cq    = (wv >> 1) * 64;
  const int nq    = (wv & 1) * 64;
  const int lrow  = lane & 15;
  const int lquad = lane >> 4;

  const float* src = x + ((size_t)b * C_ + (size_t)c_blk * CT) * HW_;
  #pragma unroll 4
  for (int p = 0; p < 24; ++p) {
    int i   = p * 256 + tid;
    int row = i / 48;
    int ch  = i - row * 48;
    const float* bp = src + row * HW_ + ch * 4;
    float v0 = 0.f, v1 = 0.f, v2 = 0.f, v3 = 0.f;
    if (ch < 42) {
      f32x4u t = *(const f32x4u*)bp;
      v0 = t[0]; v1 = t[1]; v2 = t[2]; v3 = t[3];
    } else if (ch == 42) {
      v0 = bp[0];
    }
    unsigned d0 = pack_trunc(v0, v1);
    unsigned d1 = pack_trunc(v2, v3);
    uint2 d; d.x = d0; d.y = d1;
    *(uint2*)&Xs[row * SXR + ch * 4] = d;
  }
  __syncthreads();

  const int cm0 = c_blk * 8 + (cq >> 4);

  #pragma unroll 1
  for (int nb = 0; nb < 4; ++nb) {
    const int nm0 = nb * 8 + (nq >> 4);
    const __bf16* bbase = wsf + ((size_t)nm0 * 6) * 512 + (size_t)lane * 8;

    const f32x4 zero = {0.f, 0.f, 0.f, 0.f};
    f32x4 acc[4][4];
    #pragma unroll
    for (int mi = 0; mi < 4; ++mi)
      #pragma unroll
      for (int ni = 0; ni < 4; ++ni)
        acc[mi][ni] = zero;

    #pragma unroll
    for (int kb = 0; kb < 6; ++kb) {
      bf16x8 afr[4], bfr[4];
      #pragma unroll
      for (int mi = 0; mi < 4; ++mi)
        afr[mi] = *(const bf16x8*)&Xs[(cq + mi * 16 + lrow) * SXR + kb * 32 + lquad * 8];
      #pragma unroll
      for (int ni = 0; ni < 4; ++ni)
        bfr[ni] = *(const bf16x8*)(bbase + ((size_t)ni * 6 + kb) * 512);
      #pragma unroll
      for (int mi = 0; mi < 4; ++mi)
        #pragma unroll
        for (int ni = 0; ni < 4; ++ni)
          acc[mi][ni] = __builtin_amdgcn_mfma_f32_16x16x32_bf16(
              afr[mi], bfr[ni], acc[mi][ni], 0, 0, 0);
    }

    float s[4] = {0.f, 0.f, 0.f, 0.f};
    #pragma unroll
    for (int ni = 0; ni < 4; ++ni) {
      #pragma unroll
      for (int mi = 0; mi < 4; ++mi) {
        const f32x4 w = *(const f32x4*)(wdf +
            (((size_t)(cm0 + mi) * 32 + (nm0 + ni)) * 64 + lane) * 4);
        s[ni] += acc[mi][ni][0] * w[0] + acc[mi][ni][1] * w[1]
               + acc[mi][ni][2] * w[2] + acc[mi][ni][3] * w[3];
      }
    }

    #pragma unroll
    for (int ni = 0; ni < 4; ++ni) {
      s[ni] += __shfl_xor(s[ni], 16, 64);
      s[ni] += __shfl_xor(s[ni], 32, 64);
    }
    if (lane < 16) {
      #pragma unroll
      for (int ni = 0; ni < 4; ++ni)
        red[wv][ni * 16 + lrow] = s[ni];
    }
    __syncthreads();

    if (tid < 128) {
      const int half = tid >> 6;
      const int idx  = tid & 63;
      const int n    = nb * 128 + tid;
      float v = red[half][idx] + red[half + 2][idx];
      if (c_blk == 0) v += Wb[n];
      atomicAdd(&out[(size_t)b * N_ + n], v);
    }
    __syncthreads();
  }
}

// ---------------- fallback main kernel (no workspace needed) ----------------

#define LDSS 104
#define KCH  96
#define NT   128

__global__ __launch_bounds__(256)
void conv_main_fallback(const float* __restrict__ x,
                        const float* __restrict__ Ws_g,
                        const float* __restrict__ Wd,
                        const float* __restrict__ Wb,
                        float* __restrict__ out) {
  __shared__ __align__(16) __bf16 Xs[CT][LDSS];
  __shared__ __align__(16) __bf16 Ws[NT][LDSS];

  const int tid   = threadIdx.x;
  const int n_blk = blockIdx.x;
  const int c_blk = blockIdx.y;
  const int b     = blockIdx.z;
  const int c0 = c_blk * CT;
  const int n0 = n_blk * NT;
  const int lane  = tid & 63;
  const int wv    = tid >> 6;
  const int cq    = (wv >> 1) * 64;
  const int nq    = (wv & 1) * 64;
  const int lrow  = lane & 15;
  const int lquad = lane >> 4;

  const f32x4 zero = {0.f, 0.f, 0.f, 0.f};
  f32x4 acc[4][4];
  #pragma unroll
  for (int mi = 0; mi < 4; ++mi)
    #pragma unroll
    for (int ni = 0; ni < 4; ++ni)
      acc[mi][ni] = zero;

  const float* xb  = x    + (size_t)b  * (C_ * HW_) + (size_t)c0 * HW_;
  const float* wsb = Ws_g + (size_t)n0 * HW_;

  for (int ch = 0; ch < 2; ++ch) {
    const int k0 = ch * KCH;
    __syncthreads();
    for (int e = tid; e < CT * KCH; e += 256) {
      int r   = e / KCH;
      int col = e - r * KCH;
      int k   = k0 + col;
      float vx = 0.f, vw = 0.f;
      if (k < HW_) {
        vx = xb [r * HW_ + k];
        vw = wsb[r * HW_ + k];
      }
      Xs[r][col] = f2bf(vx);
      Ws[r][col] = f2bf(vw);
    }
    __syncthreads();

    #pragma unroll
    for (int ks = 0; ks < 3; ++ks) {
      const int kc = ks * 32 + lquad * 8;
      bf16x8 afr[4], bfr[4];
      #pragma unroll
      for (int mi = 0; mi < 4; ++mi)
        afr[mi] = *(const bf16x8*)&Xs[cq + mi * 16 + lrow][kc];
      #pragma unroll
      for (int ni = 0; ni < 4; ++ni)
        bfr[ni] = *(const bf16x8*)&Ws[nq + ni * 16 + lrow][kc];
      #pragma unroll
      for (int mi = 0; mi < 4; ++mi)
        #pragma unroll
        for (int ni = 0; ni < 4; ++ni)
          acc[mi][ni] = __builtin_amdgcn_mfma_f32_16x16x32_bf16(
              afr[mi], bfr[ni], acc[mi][ni], 0, 0, 0);
    }
  }

  #pragma unroll
  for (int ni = 0; ni < 4; ++ni) {
    const int n = n0 + nq + ni * 16 + lrow;
    float sv = 0.f;
    #pragma unroll
    for (int mi = 0; mi < 4; ++mi) {
      const int cbase = c0 + cq + mi * 16 + lquad * 4;
      #pragma unroll
      for (int i = 0; i < 4; ++i)
        sv += acc[mi][ni][i] * Wd[(size_t)n * C_ + (cbase + i)];
    }
    sv += __shfl_xor(sv, 16, 64);
    sv += __shfl_xor(sv, 32, 64);
    if (lane < 16) {
      if (c_blk == 0 && cq == 0) sv += Wb[n];
      atomicAdd(&out[(size_t)b * N_ + n], sv);
    }
  }
}

extern "C" void kernel_launch(void* const* d_in, const int* in_sizes, int n_in,
                              void* d_out, int out_size, void* d_ws, size_t ws_size,
                              hipStream_t stream) {
  const float* x   = (const float*)d_in[0];   // [512,384,13,13]
  const float* Wsp = (const float*)d_in[1];   // [512,13,13]
  const float* Wd  = (const float*)d_in[2];   // [512,384]
  const float* Wb  = (const float*)d_in[3];   // [1,512]
  float* out = (float*)d_out;                 // [512,512] fp32

  const size_t need_basic = WSF_ELEMS * sizeof(__bf16) + WDF_ELEMS * sizeof(float);
  const size_t need_full  = need_basic + PART_ELEMS * sizeof(float);

  if (ws_size >= need_full) {
    __bf16* wsf  = (__bf16*)d_ws;
    float*  wdf  = (float*)(wsf + WSF_ELEMS);
    float*  partb = wdf + WDF_ELEMS;

    prep_aux_kernel<<<240, 256, 0, stream>>>(Wsp, Wd, wsf, wdf);
    conv_part<<<1536, 256, 0, stream>>>(x, wsf, wdf, partb);
    reduce_part<<<256, 256, 0, stream>>>(partb, Wb, out);
  } else if (ws_size >= need_basic) {
    __bf16* wsf = (__bf16*)d_ws;
    float*  wdf = (float*)(wsf + WSF_ELEMS);

    hipMemsetAsync(d_out, 0, (size_t)out_size * sizeof(float), stream);
    prep_aux_kernel<<<240, 256, 0, stream>>>(Wsp, Wd, wsf, wdf);
    conv_fused_v8<<<1536, 256, 0, stream>>>(x, wsf, wdf, Wb, out);
  } else {
    hipMemsetAsync(d_out, 0, (size_t)out_size * sizeof(float), stream);
    dim3 grid(N_ / NT, C_ / CT, B_);
    conv_main_fallback<<<grid, 256, 0, stream>>>(x, Wsp, Wd, Wb, out);
  }
}

// Round 9
// 238.054 us; speedup vs baseline: 1.7316x; 1.0465x over previous
//
#include <hip/hip_runtime.h>

// out[b,n] = sum_{c,hw} x[b,c,hw] * W_s[n,hw] * W_d[n,c] + W_b[n]
// B=512, C=384, N=512, HW=169 (13x13).
//
// R17 = R16 with the serial cross-lane tail removed from the nf loop.
// R16 counters: correct, no spill, 106 us, but MfmaUtil+VALUBusy ~25% =
// latency-bound. Chain arithmetic: ~200cy bfr load + ~190cy dependent MFMA
// chain + ~240cy of TWO serial shfl_xor (ds_swizzle on the LDS pipe) under
// a divergent lane<16 store. Fix: all 64 lanes fire-and-forget their raw
// partial into red[wv*4+lquad][nf*16+lrow] (ds_write_b32, nothing waits);
// the quad+wave combine happens ONCE after the barrier: each thread sums 16
// LDS rows for 2 n. red = 16 x 520 f32 (33.3 KB; +8 pad -> lquad groups on
// disjoint bank octets, 2-way = free; consecutive-n combine reads = clean).
// Everything else identical to R16: direct A-load (no staging), (256,4)
// register band (state fits 128 unified), unroll 1, no atomics, 3-slab
// part + tiny reducer, XCD swizzle.

#define B_   512
#define C_   384
#define N_   512
#define HW_  169
#define CT   128     // c-tile rows (3 c_blks per b)
#define SXR  200     // Xs row stride (v8/fallback kernels)
#define RSTR 520     // red row stride in f32 (512 + 8 pad)

#define WSF_ELEMS  ((size_t)32 * 6 * 64 * 8)       // 98,304 bf16
#define WDF_ELEMS  ((size_t)24 * 32 * 64 * 4)      // 196,608 f32
#define PART_ELEMS ((size_t)3 * B_ * N_)           // 786,432 f32 (3 MB)

typedef __bf16 bf16x8 __attribute__((ext_vector_type(8)));
typedef float f32x4  __attribute__((ext_vector_type(4)));
typedef float f32x4u __attribute__((ext_vector_type(4), aligned(4)));
typedef unsigned u32x4 __attribute__((ext_vector_type(4)));

__device__ __forceinline__ __bf16 f2bf(float f) {
  union { float f; unsigned u; } v; v.f = f;
  unsigned r = (v.u + 0x7FFFu + ((v.u >> 16) & 1u)) >> 16;   // RNE
  unsigned short s = (unsigned short)r;
  return __builtin_bit_cast(__bf16, s);
}

// hi16(a)|hi16(b)<<16 : two bf16 truncations in one v_perm
__device__ __forceinline__ unsigned pack_trunc(float a, float b) {
  return __builtin_amdgcn_perm(__builtin_bit_cast(unsigned, b),
                               __builtin_bit_cast(unsigned, a), 0x07060302u);
}

// ---------------- prep_aux: wsf (B-frag order) + wdf (C-layout order) ----------------
__global__ __launch_bounds__(256)
void prep_aux_kernel(const float* __restrict__ Ws,
                     const float* __restrict__ Wd,
                     __bf16* __restrict__ wsf,
                     float* __restrict__ wdf) {
  int t = blockIdx.x * 256 + threadIdx.x;      // 61440 total, exact
  if (t < 12288) {
    // wsf: t = (nm*6 + kb)*64 + lane ; lane(q=l>>4,m=l&15) holds Ws[nm*16+m][kb*32+q*8+j]
    int lane = t & 63;
    int fr   = t >> 6;
    int kb   = fr % 6;
    int nm   = fr / 6;
    int n    = nm * 16 + (lane & 15);
    int k0   = kb * 32 + (lane >> 4) * 8;
    const float* src = Ws + (size_t)n * HW_;
    bf16x8 v;
    #pragma unroll
    for (int j = 0; j < 8; ++j) {
      int k = k0 + j;
      float f = (k < HW_) ? src[k] : 0.f;
      v[j] = f2bf(f);
    }
    *(bf16x8*)(wsf + (size_t)t * 8) = v;
  } else {
    // wdf: t2 = (cm*32 + nm)*64 + lane; elem i = Wd[nm*16+(l&15)][cm*16+(l>>4)*4+i]
    int t2 = t - 12288;
    int lane = t2 & 63;
    int fr   = t2 >> 6;
    int nm   = fr & 31;
    int cm   = fr >> 5;
    int n    = nm * 16 + (lane & 15);
    int c0   = cm * 16 + (lane >> 4) * 4;
    f32x4 w = *(const f32x4u*)(Wd + (size_t)n * C_ + c0);
    *(f32x4*)(wdf + (size_t)t2 * 4) = w;
  }
}

// ---------------- R17 main kernel: direct A-load, no in-loop cross-lane ops ----------------
__global__ __launch_bounds__(256, 4)       // 128-total band: 4 waves/SIMD
void conv_part(const float* __restrict__ x,
               const __bf16* __restrict__ wsf,
               const float* __restrict__ wdf,
               float* __restrict__ part) {
  __shared__ float red[16 * RSTR];          // 33.3 KB — the ONLY LDS

  const int tid  = threadIdx.x;
  // XCD swizzle: the 3 c_blks of one b land on the same id%8 slot.
  const int id    = blockIdx.x;     // 0..1535
  const int slot  = id & 7;
  const int t8    = id >> 3;        // 0..191
  const int c_blk = t8 % 3;
  const int b     = (t8 / 3) * 8 + slot;

  const int lane  = tid & 63;
  const int wv    = tid >> 6;          // 4 waves; wave owns 32 c-rows (2 frags)
  const int lrow  = lane & 15;
  const int lquad = lane >> 4;

  // ---- A-fragments DIRECT from global: 12 frags, f32x4 pairs, pack in-reg ----
  bf16x8 a[2][6];
  #pragma unroll
  for (int mi = 0; mi < 2; ++mi) {
    const float* rp = x + ((size_t)b * C_ + (size_t)c_blk * CT + wv * 32 + mi * 16 + lrow) * HW_;
    #pragma unroll
    for (int kb = 0; kb < 6; ++kb) {
      const int k0 = kb * 32 + lquad * 8;
      float v0, v1, v2, v3, v4, v5, v6, v7;
      if (kb < 5 || k0 + 7 < HW_) {          // kb<=4 always safe (max 159)
        f32x4u t0 = *(const f32x4u*)(rp + k0);
        f32x4u t1 = *(const f32x4u*)(rp + k0 + 4);
        v0 = t0[0]; v1 = t0[1]; v2 = t0[2]; v3 = t0[3];
        v4 = t1[0]; v5 = t1[1]; v6 = t1[2]; v7 = t1[3];
      } else {                               // kb==5 tail: cols 168.. mostly pad
        v0 = (k0 + 0 < HW_) ? rp[k0 + 0] : 0.f;
        v1 = v2 = v3 = v4 = v5 = v6 = v7 = 0.f;
      }
      u32x4 pk;
      pk.x = pack_trunc(v0, v1);
      pk.y = pack_trunc(v2, v3);
      pk.z = pack_trunc(v4, v5);
      pk.w = pack_trunc(v6, v7);
      a[mi][kb] = __builtin_bit_cast(bf16x8, pk);
    }
  }

  const int cm0 = c_blk * 8 + wv * 2;       // global 16-c fragment row (0..23)
  const __bf16* bb = wsf + (size_t)lane * 8;
  const float*  wb = wdf + (size_t)lane * 4;
  const f32x4 zero = {0.f, 0.f, 0.f, 0.f};
  // per-lane red slot: row = wv*4+lquad, col = nf*16+lrow
  float* rslot = red + (wv * 4 + lquad) * RSTR + lrow;

  // ---- 32 n-fragments: stream B from L2, MFMA, fold, fire-and-forget write ----
  #pragma unroll 1
  for (int nf = 0; nf < 32; ++nf) {
    bf16x8 bfr[6];
    #pragma unroll
    for (int kb = 0; kb < 6; ++kb)
      bfr[kb] = *(const bf16x8*)(bb + ((size_t)nf * 6 + kb) * 512);

    f32x4 acc[2] = {zero, zero};
    #pragma unroll
    for (int kb = 0; kb < 6; ++kb)
      #pragma unroll
      for (int mi = 0; mi < 2; ++mi)
        acc[mi] = __builtin_amdgcn_mfma_f32_16x16x32_bf16(
            a[mi][kb], bfr[kb], acc[mi], 0, 0, 0);

    // fold acc * W_d (wdf C-layout, proven R7/R8 under CT=128)
    float t = 0.f;
    #pragma unroll
    for (int mi = 0; mi < 2; ++mi) {
      const f32x4 w = *(const f32x4*)(wb + (((size_t)(cm0 + mi) * 32 + nf) * 256));
      t += acc[mi][0] * w[0] + acc[mi][1] * w[1]
         + acc[mi][2] * w[2] + acc[mi][3] * w[3];
    }
    rslot[nf * 16] = t;                     // ds_write_b32, nothing waits on it
  }
  __syncthreads();   // the ONLY barrier

  // ---- combine: 256 threads x 2 n; sum 16 red rows (consecutive-n = clean) ----
  float* pb = part + ((size_t)c_blk * B_ + b) * N_;
  #pragma unroll
  for (int r = 0; r < 2; ++r) {
    const int n = r * 256 + tid;
    float v = 0.f;
    #pragma unroll
    for (int s = 0; s < 16; ++s)
      v += red[s * RSTR + n];
    pb[n] = v;
  }
}

// ---------------- reducer: out = sum of 3 slabs + bias ----------------
__global__ __launch_bounds__(256)
void reduce_part(const float* __restrict__ part,
                 const float* __restrict__ Wb,
                 float* __restrict__ out) {
  const size_t S = (size_t)B_ * N_;
  int idx = (blockIdx.x * 256 + threadIdx.x) * 4;   // 256 blocks -> covers 262144
  f32x4 a0 = *(const f32x4u*)(part + idx);
  f32x4 a1 = *(const f32x4u*)(part + S + idx);
  f32x4 a2 = *(const f32x4u*)(part + 2 * S + idx);
  f32x4 wb = *(const f32x4u*)(Wb + (idx & (N_ - 1)));
  f32x4 r;
  #pragma unroll
  for (int i = 0; i < 4; ++i)
    r[i] = a0[i] + a1[i] + a2[i] + wb[i];
  *(f32x4*)(out + idx) = r;
}

// ---------------- R8 main kernel (ws fits wsf+wdf only; 110 us proven) ----------------
__global__ __launch_bounds__(256, 3)
void conv_fused_v8(const float* __restrict__ x,
                   const __bf16* __restrict__ wsf,
                   const float* __restrict__ wdf,
                   const float* __restrict__ Wb,
                   float* __restrict__ out) {
  __shared__ __align__(16) __bf16 Xs[CT * SXR];   // 51.2 KB
  __shared__ float red[4][64];                     // 1 KB

  const int tid  = threadIdx.x;
  const int id    = blockIdx.x;     // 0..1535
  const int slot  = id & 7;
  const int t8    = id >> 3;        // 0..191
  const int c_blk = t8 % 3;
  const int b     = (t8 / 3) * 8 + slot;

  const int lane  = tid & 63;
  const int wv    = tid >> 6;          // 4 waves: 2x2 (c,n) 64x64 quadrants
  const int cq    = (wv >> 1) * 64;
  const int nq    = (wv & 1) * 64;
  const int lrow  = lane & 15;
  const int lquad = lane >> 4;

  const float* src = x + ((size_t)b * C_ + (size_t)c_blk * CT) * HW_;
  #pragma unroll 4
  for (int p = 0; p < 24; ++p) {
    int i   = p * 256 + tid;
    int row = i / 48;
    int ch  = i - row * 48;
    const float* bp = src + row * HW_ + ch * 4;
    float v0 = 0.f, v1 = 0.f, v2 = 0.f, v3 = 0.f;
    if (ch < 42) {
      f32x4u t = *(const f32x4u*)bp;
      v0 = t[0]; v1 = t[1]; v2 = t[2]; v3 = t[3];
    } else if (ch == 42) {
      v0 = bp[0];
    }
    unsigned d0 = pack_trunc(v0, v1);
    unsigned d1 = pack_trunc(v2, v3);
    uint2 d; d.x = d0; d.y = d1;
    *(uint2*)&Xs[row * SXR + ch * 4] = d;
  }
  __syncthreads();

  const int cm0 = c_blk * 8 + (cq >> 4);

  #pragma unroll 1
  for (int nb = 0; nb < 4; ++nb) {
    const int nm0 = nb * 8 + (nq >> 4);
    const __bf16* bbase = wsf + ((size_t)nm0 * 6) * 512 + (size_t)lane * 8;

    const f32x4 zero = {0.f, 0.f, 0.f, 0.f};
    f32x4 acc[4][4];
    #pragma unroll
    for (int mi = 0; mi < 4; ++mi)
      #pragma unroll
      for (int ni = 0; ni < 4; ++ni)
        acc[mi][ni] = zero;

    #pragma unroll
    for (int kb = 0; kb < 6; ++kb) {
      bf16x8 afr[4], bfr[4];
      #pragma unroll
      for (int mi = 0; mi < 4; ++mi)
        afr[mi] = *(const bf16x8*)&Xs[(cq + mi * 16 + lrow) * SXR + kb * 32 + lquad * 8];
      #pragma unroll
      for (int ni = 0; ni < 4; ++ni)
        bfr[ni] = *(const bf16x8*)(bbase + ((size_t)ni * 6 + kb) * 512);
      #pragma unroll
      for (int mi = 0; mi < 4; ++mi)
        #pragma unroll
        for (int ni = 0; ni < 4; ++ni)
          acc[mi][ni] = __builtin_amdgcn_mfma_f32_16x16x32_bf16(
              afr[mi], bfr[ni], acc[mi][ni], 0, 0, 0);
    }

    float s[4] = {0.f, 0.f, 0.f, 0.f};
    #pragma unroll
    for (int ni = 0; ni < 4; ++ni) {
      #pragma unroll
      for (int mi = 0; mi < 4; ++mi) {
        const f32x4 w = *(const f32x4*)(wdf +
            (((size_t)(cm0 + mi) * 32 + (nm0 + ni)) * 64 + lane) * 4);
        s[ni] += acc[mi][ni][0] * w[0] + acc[mi][ni][1] * w[1]
               + acc[mi][ni][2] * w[2] + acc[mi][ni][3] * w[3];
      }
    }

    #pragma unroll
    for (int ni = 0; ni < 4; ++ni) {
      s[ni] += __shfl_xor(s[ni], 16, 64);
      s[ni] += __shfl_xor(s[ni], 32, 64);
    }
    if (lane < 16) {
      #pragma unroll
      for (int ni = 0; ni < 4; ++ni)
        red[wv][ni * 16 + lrow] = s[ni];
    }
    __syncthreads();

    if (tid < 128) {
      const int half = tid >> 6;
      const int idx  = tid & 63;
      const int n    = nb * 128 + tid;
      float v = red[half][idx] + red[half + 2][idx];
      if (c_blk == 0) v += Wb[n];
      atomicAdd(&out[(size_t)b * N_ + n], v);
    }
    __syncthreads();
  }
}

// ---------------- fallback main kernel (no workspace needed) ----------------

#define LDSS 104
#define KCH  96
#define NT   128

__global__ __launch_bounds__(256)
void conv_main_fallback(const float* __restrict__ x,
                        const float* __restrict__ Ws_g,
                        const float* __restrict__ Wd,
                        const float* __restrict__ Wb,
                        float* __restrict__ out) {
  __shared__ __align__(16) __bf16 Xs[CT][LDSS];
  __shared__ __align__(16) __bf16 Ws[NT][LDSS];

  const int tid   = threadIdx.x;
  const int n_blk = blockIdx.x;
  const int c_blk = blockIdx.y;
  const int b     = blockIdx.z;
  const int c0 = c_blk * CT;
  const int n0 = n_blk * NT;
  const int lane  = tid & 63;
  const int wv    = tid >> 6;
  const int cq    = (wv >> 1) * 64;
  const int nq    = (wv & 1) * 64;
  const int lrow  = lane & 15;
  const int lquad = lane >> 4;

  const f32x4 zero = {0.f, 0.f, 0.f, 0.f};
  f32x4 acc[4][4];
  #pragma unroll
  for (int mi = 0; mi < 4; ++mi)
    #pragma unroll
    for (int ni = 0; ni < 4; ++ni)
      acc[mi][ni] = zero;

  const float* xb  = x    + (size_t)b  * (C_ * HW_) + (size_t)c0 * HW_;
  const float* wsb = Ws_g + (size_t)n0 * HW_;

  for (int ch = 0; ch < 2; ++ch) {
    const int k0 = ch * KCH;
    __syncthreads();
    for (int e = tid; e < CT * KCH; e += 256) {
      int r   = e / KCH;
      int col = e - r * KCH;
      int k   = k0 + col;
      float vx = 0.f, vw = 0.f;
      if (k < HW_) {
        vx = xb [r * HW_ + k];
        vw = wsb[r * HW_ + k];
      }
      Xs[r][col] = f2bf(vx);
      Ws[r][col] = f2bf(vw);
    }
    __syncthreads();

    #pragma unroll
    for (int ks = 0; ks < 3; ++ks) {
      const int kc = ks * 32 + lquad * 8;
      bf16x8 afr[4], bfr[4];
      #pragma unroll
      for (int mi = 0; mi < 4; ++mi)
        afr[mi] = *(const bf16x8*)&Xs[cq + mi * 16 + lrow][kc];
      #pragma unroll
      for (int ni = 0; ni < 4; ++ni)
        bfr[ni] = *(const bf16x8*)&Ws[nq + ni * 16 + lrow][kc];
      #pragma unroll
      for (int mi = 0; mi < 4; ++mi)
        #pragma unroll
        for (int ni = 0; ni < 4; ++ni)
          acc[mi][ni] = __builtin_amdgcn_mfma_f32_16x16x32_bf16(
              afr[mi], bfr[ni], acc[mi][ni], 0, 0, 0);
    }
  }

  #pragma unroll
  for (int ni = 0; ni < 4; ++ni) {
    const int n = n0 + nq + ni * 16 + lrow;
    float sv = 0.f;
    #pragma unroll
    for (int mi = 0; mi < 4; ++mi) {
      const int cbase = c0 + cq + mi * 16 + lquad * 4;
      #pragma unroll
      for (int i = 0; i < 4; ++i)
        sv += acc[mi][ni][i] * Wd[(size_t)n * C_ + (cbase + i)];
    }
    sv += __shfl_xor(sv, 16, 64);
    sv += __shfl_xor(sv, 32, 64);
    if (lane < 16) {
      if (c_blk == 0 && cq == 0) sv += Wb[n];
      atomicAdd(&out[(size_t)b * N_ + n], sv);
    }
  }
}

extern "C" void kernel_launch(void* const* d_in, const int* in_sizes, int n_in,
                              void* d_out, int out_size, void* d_ws, size_t ws_size,
                              hipStream_t stream) {
  const float* x   = (const float*)d_in[0];   // [512,384,13,13]
  const float* Wsp = (const float*)d_in[1];   // [512,13,13]
  const float* Wd  = (const float*)d_in[2];   // [512,384]
  const float* Wb  = (const float*)d_in[3];   // [1,512]
  float* out = (float*)d_out;                 // [512,512] fp32

  const size_t need_basic = WSF_ELEMS * sizeof(__bf16) + WDF_ELEMS * sizeof(float);
  const size_t need_full  = need_basic + PART_ELEMS * sizeof(float);

  if (ws_size >= need_full) {
    __bf16* wsf  = (__bf16*)d_ws;
    float*  wdf  = (float*)(wsf + WSF_ELEMS);
    float*  partb = wdf + WDF_ELEMS;

    prep_aux_kernel<<<240, 256, 0, stream>>>(Wsp, Wd, wsf, wdf);
    conv_part<<<1536, 256, 0, stream>>>(x, wsf, wdf, partb);
    reduce_part<<<256, 256, 0, stream>>>(partb, Wb, out);
  } else if (ws_size >= need_basic) {
    __bf16* wsf = (__bf16*)d_ws;
    float*  wdf = (float*)(wsf + WSF_ELEMS);

    hipMemsetAsync(d_out, 0, (size_t)out_size * sizeof(float), stream);
    prep_aux_kernel<<<240, 256, 0, stream>>>(Wsp, Wd, wsf, wdf);
    conv_fused_v8<<<1536, 256, 0, stream>>>(x, wsf, wdf, Wb, out);
  } else {
    hipMemsetAsync(d_out, 0, (size_t)out_size * sizeof(float), stream);
    dim3 grid(N_ / NT, C_ / CT, B_);
    conv_main_fallback<<<grid, 256, 0, stream>>>(x, Wsp, Wd, Wb, out);
  }
}